// Round 1
// baseline (354.491 us; speedup 1.0000x reference)
//
#include <hip/hip_runtime.h>

// Symmetry-aware Taylor attention, fp32 vector baseline.
// B=4 H=8 T=2048 d_key=32 d_val=64, N_TAYLOR=4 (w = 1 + x + x^2/2 + x^3/6).
// out[q] = (sum_{k<=q} w(x_qk) * V[k]) / (sum_{k<=q} w(x_qk)),  x = (q.k)/sqrt(32)

namespace {

constexpr int T_SEQ = 2048;
constexpr int DK    = 32;
constexpr int DV    = 64;
constexpr int QT    = 128;   // query rows per block
constexpr int KTile = 32;    // keys per inner tile
constexpr int NQT   = T_SEQ / QT;   // 16
constexpr int NBH   = 32;           // B*H
constexpr float SCALE = 0.17677669529663687f;  // 1/sqrt(32)

__global__ __launch_bounds__(256, 3)
void taylor_attn(const float* __restrict__ Qg, const float* __restrict__ Kg,
                 const float* __restrict__ Vg, float* __restrict__ Outg) {
  // LDS: 16 + 4 + 8 + 16 + 4 = 48 KB -> 3 blocks/CU
  __shared__ float Qs[QT * DK];      // swizzled granules (4-float), 16 KB
  __shared__ float Ks[KTile * DK];   // row-major, 4 KB (reads are broadcast)
  __shared__ float Vs[KTile * DV];   // row-major, 8 KB (reads are broadcast)
  __shared__ float Ws[KTile * QT];   // W[k][q], 16 KB
  __shared__ float Zs[8 * QT];       // per-kg partial Z, 4 KB

  const int tid = threadIdx.x;
  const int qg  = tid & 31;   // q-group: rows 4*qg..+3   (phases A, B, output)
  const int kg  = tid >> 5;   // 0..7: k-group (A) / c-group of 8 (B, output)

  const int bid   = blockIdx.x;
  const int qi    = bid >> 5;          // 0..15
  const int bh    = bid & 31;
  const int qtile = (NQT - 1) - qi;    // heavy tiles first (load balance)
  const int q0    = qtile * QT;

  const float* Qbase = Qg + (size_t)bh * T_SEQ * DK;
  const float* Kbase = Kg + (size_t)bh * T_SEQ * DK;
  const float* Vbase = Vg + (size_t)bh * T_SEQ * DV;

  // ---- stage Q tile once, XOR-swizzled on 4-float granules:
  //      granule g of row r stored at g ^ ((r>>2)&7). Kills the stride-128B
  //      bank conflict on phase-A column-ish reads (16-way -> ~2-way).
  {
    const float4* src = (const float4*)(Qbase + (size_t)q0 * DK);
    float4* dst = (float4*)Qs;
#pragma unroll
    for (int p = 0; p < 4; ++p) {
      int e4  = tid + p * 256;       // 0..1023
      int row = e4 >> 3;             // 0..127
      int gr  = e4 & 7;
      dst[row * 8 + (gr ^ ((row >> 2) & 7))] = src[e4];
    }
  }

  float accS[4][8];
#pragma unroll
  for (int i = 0; i < 4; ++i)
#pragma unroll
    for (int j = 0; j < 8; ++j) accS[i][j] = 0.f;
  float zacc[4] = {0.f, 0.f, 0.f, 0.f};

  const int nkt = 4 * (qtile + 1);   // key tiles: cover keys [0, q0+QT)

  for (int kt = 0; kt < nkt; ++kt) {
    const int k0 = kt * KTile;

    __syncthreads();  // prev phase B done reading Vs/Ws; Qs ready (iter 0)

    // ---- stage K (256 float4, 1/thread) and V (512 float4, 2/thread)
    {
      const float4* ksrc = (const float4*)(Kbase + (size_t)k0 * DK);
      ((float4*)Ks)[tid] = ksrc[tid];
      const float4* vsrc = (const float4*)(Vbase + (size_t)k0 * DV);
      ((float4*)Vs)[tid]       = vsrc[tid];
      ((float4*)Vs)[tid + 256] = vsrc[tid + 256];
    }
    __syncthreads();

    // ---- phase A: 4q x 4k scores -> poly -> mask -> Ws, zacc
    {
      float dot[4][4];
#pragma unroll
      for (int i = 0; i < 4; ++i)
#pragma unroll
        for (int j = 0; j < 4; ++j) dot[i][j] = 0.f;

#pragma unroll
      for (int dc = 0; dc < 8; ++dc) {
        float4 qv[4], kv[4];
#pragma unroll
        for (int i = 0; i < 4; ++i) {
          int row = qg * 4 + i;
          qv[i] = *(const float4*)&Qs[row * 32 + ((dc ^ (qg & 7)) * 4)];
        }
#pragma unroll
        for (int j = 0; j < 4; ++j) {
          kv[j] = *(const float4*)&Ks[(kg * 4 + j) * 32 + dc * 4];  // broadcast
        }
#pragma unroll
        for (int i = 0; i < 4; ++i)
#pragma unroll
          for (int j = 0; j < 4; ++j) {
            dot[i][j] += qv[i].x * kv[j].x;
            dot[i][j] += qv[i].y * kv[j].y;
            dot[i][j] += qv[i].z * kv[j].z;
            dot[i][j] += qv[i].w * kv[j].w;
          }
      }

#pragma unroll
      for (int j = 0; j < 4; ++j) {
        const int gk = k0 + kg * 4 + j;
        float4 wj;
        float* wp = (float*)&wj;
#pragma unroll
        for (int i = 0; i < 4; ++i) {
          const int q = q0 + qg * 4 + i;
          float x = dot[i][j] * SCALE;
          // Horner exactly as reference: 1 + x*(1 + (x/2)*(1 + (x/3)))
          float t3 = 1.f + x * 0.33333334f;
          float t2 = 1.f + 0.5f * x * t3;
          float w  = 1.f + x * t2;
          w = (gk <= q) ? w : 0.f;   // causal mask (diag included)
          wp[i] = w;
          zacc[i] += w;
        }
        *(float4*)&Ws[(kg * 4 + j) * QT + qg * 4] = wj;  // [k][q], 2-way max
      }
    }
    __syncthreads();

    // ---- phase B: accS[4q][8c] += W[k][4q] * V[k][8c]
    {
      const int c8 = kg * 8;
#pragma unroll 4
      for (int k = 0; k < KTile; ++k) {
        float4 w4 = *(const float4*)&Ws[k * QT + qg * 4];   // conflict-free
        float4 va = *(const float4*)&Vs[k * DV + c8];       // broadcast
        float4 vb = *(const float4*)&Vs[k * DV + c8 + 4];   // broadcast
        const float* wf = (const float*)&w4;
        const float* v0 = (const float*)&va;
        const float* v1 = (const float*)&vb;
#pragma unroll
        for (int i = 0; i < 4; ++i)
#pragma unroll
          for (int j = 0; j < 4; ++j) {
            accS[i][j]     += wf[i] * v0[j];
            accS[i][j + 4] += wf[i] * v1[j];
          }
      }
    }
  }

  // ---- reduce Z across the 8 kg groups
  {
    float4 zv;
    zv.x = zacc[0]; zv.y = zacc[1]; zv.z = zacc[2]; zv.w = zacc[3];
    *(float4*)&Zs[kg * QT + qg * 4] = zv;
  }
  __syncthreads();

  float z[4] = {0.f, 0.f, 0.f, 0.f};
#pragma unroll
  for (int g = 0; g < 8; ++g) {
    float4 zp = *(const float4*)&Zs[g * QT + qg * 4];
    z[0] += zp.x; z[1] += zp.y; z[2] += zp.z; z[3] += zp.w;
  }

  // ---- write out: rows 4*qg..+3, cols kg*8..+7
  float* obase = Outg + ((size_t)bh * T_SEQ + (size_t)q0) * DV;
  const int c8 = kg * 8;
#pragma unroll
  for (int i = 0; i < 4; ++i) {
    const float inv = 1.f / z[i];
    const int row = qg * 4 + i;
    float4 oa, ob;
    oa.x = accS[i][0] * inv; oa.y = accS[i][1] * inv;
    oa.z = accS[i][2] * inv; oa.w = accS[i][3] * inv;
    ob.x = accS[i][4] * inv; ob.y = accS[i][5] * inv;
    ob.z = accS[i][6] * inv; ob.w = accS[i][7] * inv;
    *(float4*)&obase[row * DV + c8]     = oa;
    *(float4*)&obase[row * DV + c8 + 4] = ob;
  }
}

}  // namespace

extern "C" void kernel_launch(void* const* d_in, const int* in_sizes, int n_in,
                              void* d_out, int out_size, void* d_ws, size_t ws_size,
                              hipStream_t stream) {
  const float* Q = (const float*)d_in[0];
  const float* K = (const float*)d_in[1];
  const float* V = (const float*)d_in[2];
  float* Out = (float*)d_out;

  dim3 grid(NQT * NBH);   // 512 blocks: (16 q-tiles, heavy first) x 32 (b,h)
  dim3 block(256);
  hipLaunchKernelGGL(taylor_attn, grid, block, 0, stream, Q, K, V, Out);
}

// Round 2
// 119.893 us; speedup vs baseline: 2.9567x; 2.9567x over previous
//
#include <hip/hip_runtime.h>

// Split-bf16 MFMA implementation of Taylor attention.
// B=4 H=8 T=2048 d_key=32 d_val=64, N_TAYLOR=4.
// fp32 x ~= hi + lo (bf16 truncation + bf16 residual); products via 3 MFMAs:
// hi*hi + hi*lo + lo*hi, rel err ~2^-16. Used for QK^T and for W*V.

typedef __attribute__((ext_vector_type(8))) short bf16x8;
typedef __attribute__((ext_vector_type(4))) float f32x4;

namespace {

constexpr int T_SEQ = 2048;
constexpr int DK    = 32;
constexpr int DV    = 64;
constexpr int QT    = 64;    // query rows per block (4 waves x 16)
constexpr int KT    = 32;    // keys per step
constexpr int LDSW  = 40;    // padded LDS row stride in ushorts (80B, 16B-aligned)
constexpr float SCALE = 0.17677669529663687f;  // 1/sqrt(32)

__device__ __forceinline__ unsigned pack_hi2(float f0, float f1) {
  // bf16(f0) | bf16(f1)<<16   (truncation)
  return (__float_as_uint(f0) >> 16) | (__float_as_uint(f1) & 0xffff0000u);
}
__device__ __forceinline__ float trunc_bf(float f) {
  return __uint_as_float(__float_as_uint(f) & 0xffff0000u);
}

__global__ __launch_bounds__(256, 4)
void taylor_attn_mfma(const float* __restrict__ Qg, const float* __restrict__ Kg,
                      const float* __restrict__ Vg, float* __restrict__ Outg) {
  // LDS: Q 10240 + K 5120 + Vt 10240 + W 8192 = 33792 B -> 4 blocks/CU
  __shared__ __align__(16) unsigned short Qhi[QT * LDSW], Qlo[QT * LDSW];
  __shared__ __align__(16) unsigned short Khi[KT * LDSW], Klo[KT * LDSW];
  __shared__ __align__(16) unsigned short Vthi[DV * LDSW], Vtlo[DV * LDSW];
  __shared__ __align__(16) unsigned Wp[4][16 * 32];  // per-wave packed hi|lo weights

  const int tid  = threadIdx.x;
  const int lane = tid & 63;
  const int wid  = tid >> 6;
  const int m    = lane & 15;   // frag row/col selector
  const int g    = lane >> 4;   // frag k-chunk selector

  // XCD-aware decode: 8 XCDs each own 4 bh (K/V set = 3MB, L2-resident);
  // within an XCD, q-tiles descend (heavy-first for load balance).
  const int bid = blockIdx.x;
  const int v   = bid >> 3;
  const int bh  = (bid & 7) * 4 + (v >> 5);
  const int qt  = 31 - (v & 31);
  const int q0  = qt * QT;

  const float* Qbase = Qg + ((size_t)bh * T_SEQ + q0) * DK;
  const float* Kbase = Kg + (size_t)bh * T_SEQ * DK;
  const float* Vbase = Vg + (size_t)bh * T_SEQ * DV;

  // ---- stage Q tile -> bf16 hi/lo (once per block)
#pragma unroll
  for (int p = 0; p < 2; ++p) {
    int e   = tid + p * 256;         // 0..511
    int row = e >> 3;                // 0..63
    int c4  = (e & 7) * 4;           // 0..28
    float4 f = *(const float4*)(Qbase + row * DK + c4);
    uint2 h, l;
    h.x = pack_hi2(f.x, f.y);
    h.y = pack_hi2(f.z, f.w);
    l.x = pack_hi2(f.x - trunc_bf(f.x), f.y - trunc_bf(f.y));
    l.y = pack_hi2(f.z - trunc_bf(f.z), f.w - trunc_bf(f.w));
    *(uint2*)&Qhi[row * LDSW + c4] = h;
    *(uint2*)&Qlo[row * LDSW + c4] = l;
  }
  __syncthreads();

  // ---- hoist this wave's Q fragments (A-frag: row=lane&15, k-chunk=lane>>4)
  const int wq = wid * 16;
  const bf16x8 qhi = *(const bf16x8*)&Qhi[(wq + m) * LDSW + g * 8];
  const bf16x8 qlo = *(const bf16x8*)&Qlo[(wq + m) * LDSW + g * 8];

  f32x4 acc[4];
#pragma unroll
  for (int ct = 0; ct < 4; ++ct) acc[ct] = f32x4{0.f, 0.f, 0.f, 0.f};
  float zacc[4] = {0.f, 0.f, 0.f, 0.f};

  const int q_lane0 = q0 + wq + g * 4;   // D rows: q_lane0 + r
  const int q_wave_max = q0 + wq + 15;

  const int nkt = (q0 + QT) / KT;
  for (int kt = 0; kt < nkt; ++kt) {
    const int k0 = kt * KT;

    __syncthreads();  // prev step's reads of K/Vt complete

    // ---- stage K tile (32x32) -> Khi/Klo
    {
      int row = tid >> 3;            // 0..31
      int c4  = (tid & 7) * 4;       // 0..28
      float4 f = *(const float4*)(Kbase + (size_t)(k0 + row) * DK + c4);
      uint2 h, l;
      h.x = pack_hi2(f.x, f.y);
      h.y = pack_hi2(f.z, f.w);
      l.x = pack_hi2(f.x - trunc_bf(f.x), f.y - trunc_bf(f.y));
      l.y = pack_hi2(f.z - trunc_bf(f.z), f.w - trunc_bf(f.w));
      *(uint2*)&Khi[row * LDSW + c4] = h;
      *(uint2*)&Klo[row * LDSW + c4] = l;
    }
    // ---- stage V tile (32x64) transposed -> Vthi/Vtlo [c][k]
    {
      int kk = (tid & 15) * 2;       // 0..30 (even)
      int c4 = (tid >> 4) * 4;       // 0..60
      const float* vp = Vbase + (size_t)(k0 + kk) * DV + c4;
      float4 a = *(const float4*)vp;
      float4 b = *(const float4*)(vp + DV);
      float af[4] = {a.x, a.y, a.z, a.w};
      float bf[4] = {b.x, b.y, b.z, b.w};
#pragma unroll
      for (int j = 0; j < 4; ++j) {
        unsigned hi = pack_hi2(af[j], bf[j]);
        unsigned lo = pack_hi2(af[j] - trunc_bf(af[j]), bf[j] - trunc_bf(bf[j]));
        *(unsigned*)&Vthi[(c4 + j) * LDSW + kk] = hi;  // conflict-free by map
        *(unsigned*)&Vtlo[(c4 + j) * LDSW + kk] = lo;
      }
    }
    __syncthreads();

    if (k0 > q_wave_max) continue;   // fully-masked step for this wave

    // ---- phase A: scores (3-MFMA split), poly, mask, Z, pack W -> LDS
#pragma unroll
    for (int k16 = 0; k16 < 2; ++k16) {
      const int kcol0 = k16 * 16;
      bf16x8 khi = *(const bf16x8*)&Khi[(kcol0 + m) * LDSW + g * 8];
      bf16x8 klo = *(const bf16x8*)&Klo[(kcol0 + m) * LDSW + g * 8];
      f32x4 s = {0.f, 0.f, 0.f, 0.f};
      s = __builtin_amdgcn_mfma_f32_16x16x32_bf16(qhi, khi, s, 0, 0, 0);
      s = __builtin_amdgcn_mfma_f32_16x16x32_bf16(qhi, klo, s, 0, 0, 0);
      s = __builtin_amdgcn_mfma_f32_16x16x32_bf16(qlo, khi, s, 0, 0, 0);
      const int k_abs = k0 + kcol0 + m;
      const int kcol  = kcol0 + m;
#pragma unroll
      for (int r = 0; r < 4; ++r) {
        float x  = s[r] * SCALE;
        float a3 = __builtin_fmaf(x, 0.3333333333333333f, 1.0f);  // 1 + x/3
        float a2 = __builtin_fmaf(x * 0.5f, a3, 1.0f);            // 1 + x/2*a3
        float w  = __builtin_fmaf(x, a2, 1.0f);                   // 1 + x*a2
        w = (k_abs <= q_lane0 + r) ? w : 0.0f;                    // causal
        zacc[r] += w;
        float wl = w - trunc_bf(w);
        unsigned packed = (__float_as_uint(w) >> 16) |
                          (__float_as_uint(wl) & 0xffff0000u);
        const int q = g * 4 + r;
        // XOR-granule swizzle: 2-way max on write and read
        Wp[wid][q * 32 + (((kcol >> 2) ^ (q & 7)) << 2) + (kcol & 3)] = packed;
      }
    }

    // ---- phase B: A-frag of W (row=m, k=g*8..+7) from swizzled granules
    uint4 pa = *(const uint4*)&Wp[wid][m * 32 + (((2 * g) ^ (m & 7)) << 2)];
    uint4 pb = *(const uint4*)&Wp[wid][m * 32 + (((2 * g + 1) ^ (m & 7)) << 2)];
    union { bf16x8 v; unsigned u[4]; } WH, WL;
    WH.u[0] = (pa.x & 0xffffu) | (pa.y << 16);
    WH.u[1] = (pa.z & 0xffffu) | (pa.w << 16);
    WH.u[2] = (pb.x & 0xffffu) | (pb.y << 16);
    WH.u[3] = (pb.z & 0xffffu) | (pb.w << 16);
    WL.u[0] = (pa.x >> 16) | (pa.y & 0xffff0000u);
    WL.u[1] = (pa.z >> 16) | (pa.w & 0xffff0000u);
    WL.u[2] = (pb.x >> 16) | (pb.y & 0xffff0000u);
    WL.u[3] = (pb.z >> 16) | (pb.w & 0xffff0000u);

#pragma unroll
    for (int ct = 0; ct < 4; ++ct) {
      bf16x8 vhi = *(const bf16x8*)&Vthi[(ct * 16 + m) * LDSW + g * 8];
      bf16x8 vlo = *(const bf16x8*)&Vtlo[(ct * 16 + m) * LDSW + g * 8];
      acc[ct] = __builtin_amdgcn_mfma_f32_16x16x32_bf16(WH.v, vhi, acc[ct], 0, 0, 0);
      acc[ct] = __builtin_amdgcn_mfma_f32_16x16x32_bf16(WH.v, vlo, acc[ct], 0, 0, 0);
      acc[ct] = __builtin_amdgcn_mfma_f32_16x16x32_bf16(WL.v, vhi, acc[ct], 0, 0, 0);
    }
  }

  // ---- Z reduce across the 16 k-lanes of each quarter-group
  float invz[4];
#pragma unroll
  for (int r = 0; r < 4; ++r) {
    float z = zacc[r];
    z += __shfl_xor(z, 1);
    z += __shfl_xor(z, 2);
    z += __shfl_xor(z, 4);
    z += __shfl_xor(z, 8);
    invz[r] = 1.0f / z;
  }

  // ---- epilogue: out[q][c] = acc/Z   (row = g*4+r, col = ct*16+m)
  float* ob = Outg + ((size_t)bh * T_SEQ + (q0 + wq)) * DV;
#pragma unroll
  for (int ct = 0; ct < 4; ++ct)
#pragma unroll
    for (int r = 0; r < 4; ++r)
      ob[(g * 4 + r) * DV + ct * 16 + m] = acc[ct][r] * invz[r];
}

}  // namespace

extern "C" void kernel_launch(void* const* d_in, const int* in_sizes, int n_in,
                              void* d_out, int out_size, void* d_ws, size_t ws_size,
                              hipStream_t stream) {
  const float* Q = (const float*)d_in[0];
  const float* K = (const float*)d_in[1];
  const float* V = (const float*)d_in[2];
  float* Out = (float*)d_out;

  dim3 grid(32 * 32);   // 1024 blocks: 8 XCD groups x 4 bh x 32 q-tiles
  dim3 block(256);
  hipLaunchKernelGGL(taylor_attn_mfma, grid, block, 0, stream, Q, K, V, Out);
}

// Round 3
// 117.835 us; speedup vs baseline: 3.0084x; 1.0175x over previous
//
#include <hip/hip_runtime.h>

// Taylor attention v3: pre-packed split-bf16 K/V fragments in workspace,
// barrier-free MFMA main loop, R=32 q-rows/wave, 4-way K-split per block
// with LDS combine. Falls back to the v2 (staged-LDS) kernel if ws is small.

typedef __attribute__((ext_vector_type(8))) short bf16x8;
typedef __attribute__((ext_vector_type(4))) float f32x4;
typedef unsigned int u32;
typedef unsigned short u16;

namespace {

constexpr int T_SEQ = 2048;
constexpr int DK    = 32;
constexpr int DV    = 64;
constexpr int NBH   = 32;
constexpr float SCALE = 0.17677669529663687f;  // 1/sqrt(32)

// workspace layout (bytes)
constexpr size_t KHI_OFF  = 0;
constexpr size_t KLO_OFF  = (size_t)NBH * T_SEQ * DK * 2;            //  4 MiB
constexpr size_t VTHI_OFF = KLO_OFF * 2;                             //  8 MiB
constexpr size_t VTLO_OFF = VTHI_OFF + (size_t)NBH * DV * T_SEQ * 2; // 16 MiB
constexpr size_t WS_NEED  = VTLO_OFF + (size_t)NBH * DV * T_SEQ * 2; // 24 MiB

__device__ __forceinline__ unsigned pack_hi2(float f0, float f1) {
  return (__float_as_uint(f0) >> 16) | (__float_as_uint(f1) & 0xffff0000u);
}
__device__ __forceinline__ float trunc_bf(float f) {
  return __uint_as_float(__float_as_uint(f) & 0xffff0000u);
}
__device__ __forceinline__ u16 bfhi(float f) { return (u16)(__float_as_uint(f) >> 16); }

// ---------------- pack kernels ----------------

__global__ void pack_k(const float* __restrict__ Kg, u16* __restrict__ Khi,
                       u16* __restrict__ Klo) {
  size_t i = ((size_t)blockIdx.x * 256 + threadIdx.x) * 4;
  float4 f = *(const float4*)(Kg + i);
  ushort4 h, l;
  h.x = bfhi(f.x); h.y = bfhi(f.y); h.z = bfhi(f.z); h.w = bfhi(f.w);
  l.x = bfhi(f.x - trunc_bf(f.x)); l.y = bfhi(f.y - trunc_bf(f.y));
  l.z = bfhi(f.z - trunc_bf(f.z)); l.w = bfhi(f.w - trunc_bf(f.w));
  *(ushort4*)(Khi + i) = h;
  *(ushort4*)(Klo + i) = l;
}

// V[bh][k][c] -> Vt{hi,lo}[bh][c][k]  (32-k x 64-c tiles via LDS)
__global__ void pack_v(const float* __restrict__ Vg, u16* __restrict__ Vthi,
                       u16* __restrict__ Vtlo) {
  __shared__ float tile[DV][33];
  const int bid = blockIdx.x;
  const int bh  = bid >> 6;
  const int k0  = (bid & 63) * 32;
  const int t   = threadIdx.x;
  {
    const int kl = t >> 3, c0 = (t & 7) * 8;
    const float* src = Vg + ((size_t)bh * T_SEQ + k0 + kl) * DV + c0;
    float4 a = *(const float4*)src;
    float4 b = *(const float4*)(src + 4);
    tile[c0 + 0][kl] = a.x; tile[c0 + 1][kl] = a.y;
    tile[c0 + 2][kl] = a.z; tile[c0 + 3][kl] = a.w;
    tile[c0 + 4][kl] = b.x; tile[c0 + 5][kl] = b.y;
    tile[c0 + 6][kl] = b.z; tile[c0 + 7][kl] = b.w;
  }
  __syncthreads();
  {
    const int cl = t >> 2, k8 = (t & 3) * 8;
    u32 h[4], l[4];
#pragma unroll
    for (int j = 0; j < 4; ++j) {
      float v0 = tile[cl][k8 + 2 * j];
      float v1 = tile[cl][k8 + 2 * j + 1];
      h[j] = pack_hi2(v0, v1);
      l[j] = pack_hi2(v0 - trunc_bf(v0), v1 - trunc_bf(v1));
    }
    size_t off = ((size_t)(bh * DV + cl)) * T_SEQ + k0 + k8;
    *(uint4*)(Vthi + off) = make_uint4(h[0], h[1], h[2], h[3]);
    *(uint4*)(Vtlo + off) = make_uint4(l[0], l[1], l[2], l[3]);
  }
}

// ---------------- main kernel (v3) ----------------

__global__ __launch_bounds__(256, 3)
void taylor_attn_v3(const float* __restrict__ Qg, const u16* __restrict__ Khi,
                    const u16* __restrict__ Klo, const u16* __restrict__ Vthi,
                    const u16* __restrict__ Vtlo, float* __restrict__ Outg) {
  // 4 waves x 2048 floats (first 1024 floats of each slice double as the
  // per-wave W-transpose buffer during the loop) + Z partials.
  __shared__ __align__(16) float Comb[4 * 2048];   // 32 KB
  __shared__ float Zs[4 * 32];                     // 512 B

  const int tid  = threadIdx.x;
  const int lane = tid & 63;
  const int w    = tid >> 6;
  const int m    = lane & 15;
  const int g    = lane >> 4;

  // decode: 8 XCD groups x 4 bh x 64 strips, strips descending (heavy first)
  const int bid = blockIdx.x;
  const int xcd = bid & 7;
  const int u   = bid >> 3;
  const int bh  = xcd * 4 + (u >> 6);
  const int s   = 63 - (u & 63);          // 32-row strip index
  const int q0  = s * 32;

  const int steps = s + 1;                // kt-steps of 32 keys
  const int cch   = (steps + 3) >> 2;
  const int kt0   = w * cch;
  const int kt1   = min(kt0 + cch, steps);

  u32* Wbuf = (u32*)(Comb + w * 2048);    // [qf][16 q][32 k] packed hi|lo

  // ---- Q fragments (packed on the fly; once per wave)
  bf16x8 qhi[2], qlo[2];
#pragma unroll
  for (int qf = 0; qf < 2; ++qf) {
    const float* qp = Qg + ((size_t)bh * T_SEQ + q0 + qf * 16 + m) * DK + g * 8;
    float4 a = *(const float4*)qp;
    float4 b = *(const float4*)(qp + 4);
    union { bf16x8 v; u32 u[4]; } H, L;
    H.u[0] = pack_hi2(a.x, a.y); H.u[1] = pack_hi2(a.z, a.w);
    H.u[2] = pack_hi2(b.x, b.y); H.u[3] = pack_hi2(b.z, b.w);
    L.u[0] = pack_hi2(a.x - trunc_bf(a.x), a.y - trunc_bf(a.y));
    L.u[1] = pack_hi2(a.z - trunc_bf(a.z), a.w - trunc_bf(a.w));
    L.u[2] = pack_hi2(b.x - trunc_bf(b.x), b.y - trunc_bf(b.y));
    L.u[3] = pack_hi2(b.z - trunc_bf(b.z), b.w - trunc_bf(b.w));
    qhi[qf] = H.v; qlo[qf] = L.v;
  }

  f32x4 acc[2][4];
#pragma unroll
  for (int qf = 0; qf < 2; ++qf)
#pragma unroll
    for (int ct = 0; ct < 4; ++ct) acc[qf][ct] = f32x4{0.f, 0.f, 0.f, 0.f};
  float zacc[2][4] = {{0.f, 0.f, 0.f, 0.f}, {0.f, 0.f, 0.f, 0.f}};

  const u16* kbh_hi = Khi + (size_t)bh * T_SEQ * DK;
  const u16* kbh_lo = Klo + (size_t)bh * T_SEQ * DK;
  const u16* vbh_hi = Vthi + (size_t)bh * DV * T_SEQ;
  const u16* vbh_lo = Vtlo + (size_t)bh * DV * T_SEQ;

  for (int kt = kt0; kt < kt1; ++kt) {
    const int k0 = kt * 32;
    const bool need_mask = (kt == s);

    // ---- K fragments (global, L2-hot)
    bf16x8 khi[2], klo[2];
#pragma unroll
    for (int k16 = 0; k16 < 2; ++k16) {
      size_t off = (size_t)(k0 + k16 * 16 + m) * DK + g * 8;
      khi[k16] = *(const bf16x8*)(kbh_hi + off);
      klo[k16] = *(const bf16x8*)(kbh_lo + off);
    }

    // ---- scores -> poly -> (mask) -> Z, pack W into per-wave LDS
#pragma unroll
    for (int k16 = 0; k16 < 2; ++k16) {
      const int kcol = k16 * 16 + m;
#pragma unroll
      for (int qf = 0; qf < 2; ++qf) {
        f32x4 sc = {0.f, 0.f, 0.f, 0.f};
        sc = __builtin_amdgcn_mfma_f32_16x16x32_bf16(qhi[qf], khi[k16], sc, 0, 0, 0);
        sc = __builtin_amdgcn_mfma_f32_16x16x32_bf16(qhi[qf], klo[k16], sc, 0, 0, 0);
        sc = __builtin_amdgcn_mfma_f32_16x16x32_bf16(qlo[qf], khi[k16], sc, 0, 0, 0);
#pragma unroll
        for (int r = 0; r < 4; ++r) {
          float x  = sc[r] * SCALE;
          float a3 = __builtin_fmaf(x, 0.3333333333333333f, 1.0f);
          float a2 = __builtin_fmaf(x * 0.5f, a3, 1.0f);
          float wv = __builtin_fmaf(x, a2, 1.0f);
          if (need_mask) {
            const int q_rel = qf * 16 + g * 4 + r;
            wv = (kcol <= q_rel) ? wv : 0.0f;
          }
          zacc[qf][r] += wv;
          float wl = wv - trunc_bf(wv);
          u32 packed = (__float_as_uint(wv) >> 16) |
                       (__float_as_uint(wl) & 0xffff0000u);
          const int q = g * 4 + r;
          Wbuf[qf * 512 + q * 32 + ((((kcol >> 2) ^ (q & 7))) << 2) + (kcol & 3)] = packed;
        }
      }
    }

    // ---- A-fragments of W (row=m, k=g*8..g*8+7), de-swizzled
    bf16x8 WHf[2], WLf[2];
#pragma unroll
    for (int qf = 0; qf < 2; ++qf) {
      uint4 pa = *(const uint4*)&Wbuf[qf * 512 + m * 32 + (((2 * g) ^ (m & 7)) << 2)];
      uint4 pb = *(const uint4*)&Wbuf[qf * 512 + m * 32 + (((2 * g + 1) ^ (m & 7)) << 2)];
      union { bf16x8 v; u32 u[4]; } WH, WL;
      WH.u[0] = (pa.x & 0xffffu) | (pa.y << 16);
      WH.u[1] = (pa.z & 0xffffu) | (pa.w << 16);
      WH.u[2] = (pb.x & 0xffffu) | (pb.y << 16);
      WH.u[3] = (pb.z & 0xffffu) | (pb.w << 16);
      WL.u[0] = (pa.x >> 16) | (pa.y & 0xffff0000u);
      WL.u[1] = (pa.z >> 16) | (pa.w & 0xffff0000u);
      WL.u[2] = (pb.x >> 16) | (pb.y & 0xffff0000u);
      WL.u[3] = (pb.z >> 16) | (pb.w & 0xffff0000u);
      WHf[qf] = WH.v; WLf[qf] = WL.v;
    }

    // ---- PV: acc[qf][ct] += W * Vt  (V fragments global, L2-hot)
#pragma unroll
    for (int ct = 0; ct < 4; ++ct) {
      size_t voff = (size_t)(ct * 16 + m) * T_SEQ + k0 + g * 8;
      bf16x8 vhi = *(const bf16x8*)(vbh_hi + voff);
      bf16x8 vlo = *(const bf16x8*)(vbh_lo + voff);
#pragma unroll
      for (int qf = 0; qf < 2; ++qf) {
        acc[qf][ct] = __builtin_amdgcn_mfma_f32_16x16x32_bf16(WHf[qf], vhi, acc[qf][ct], 0, 0, 0);
        acc[qf][ct] = __builtin_amdgcn_mfma_f32_16x16x32_bf16(WHf[qf], vlo, acc[qf][ct], 0, 0, 0);
        acc[qf][ct] = __builtin_amdgcn_mfma_f32_16x16x32_bf16(WLf[qf], vhi, acc[qf][ct], 0, 0, 0);
      }
    }
  }

  // ---- per-wave Z reduce over the 16 k-lanes (m bits = lane bits 0..3)
#pragma unroll
  for (int qf = 0; qf < 2; ++qf)
#pragma unroll
    for (int r = 0; r < 4; ++r) {
      float z = zacc[qf][r];
      z += __shfl_xor(z, 1);
      z += __shfl_xor(z, 2);
      z += __shfl_xor(z, 4);
      z += __shfl_xor(z, 8);
      if (m == 0) Zs[w * 32 + qf * 16 + g * 4 + r] = z;
    }

  // ---- write S partials (clobbers the W region — last W read is done)
#pragma unroll
  for (int qf = 0; qf < 2; ++qf)
#pragma unroll
    for (int ct = 0; ct < 4; ++ct)
#pragma unroll
      for (int r = 0; r < 4; ++r)
        Comb[w * 2048 + (qf * 16 + g * 4 + r) * 64 + ct * 16 + m] = acc[qf][ct][r];

  __syncthreads();

  // ---- combine 4 wave-partials, divide by Z, store
  const f32x4* C4 = (const f32x4*)Comb;
#pragma unroll
  for (int i = 0; i < 2; ++i) {
    const int e4  = tid + i * 256;        // 0..511
    const int row = e4 >> 4;              // 0..31
    f32x4 ssum = C4[e4] + C4[512 + e4] + C4[1024 + e4] + C4[1536 + e4];
    float z = Zs[row] + Zs[32 + row] + Zs[64 + row] + Zs[96 + row];
    float inv = 1.0f / z;
    float4 o;
    o.x = ssum[0] * inv; o.y = ssum[1] * inv;
    o.z = ssum[2] * inv; o.w = ssum[3] * inv;
    *(float4*)(Outg + ((size_t)bh * T_SEQ + q0 + row) * DV + (e4 & 15) * 4) = o;
  }
}

// ---------------- fallback: round-2 staged-LDS kernel ----------------

constexpr int QT_FB = 64;
constexpr int KT_FB = 32;
constexpr int LDSW  = 40;

__global__ __launch_bounds__(256, 4)
void taylor_attn_fb(const float* __restrict__ Qg, const float* __restrict__ Kg,
                    const float* __restrict__ Vg, float* __restrict__ Outg) {
  __shared__ __align__(16) unsigned short Qhi[QT_FB * LDSW], Qlo[QT_FB * LDSW];
  __shared__ __align__(16) unsigned short Khi_[KT_FB * LDSW], Klo_[KT_FB * LDSW];
  __shared__ __align__(16) unsigned short Vthi_[DV * LDSW], Vtlo_[DV * LDSW];
  __shared__ __align__(16) unsigned Wp[4][16 * 32];

  const int tid  = threadIdx.x;
  const int lane = tid & 63;
  const int wid  = tid >> 6;
  const int m    = lane & 15;
  const int g    = lane >> 4;

  const int bid = blockIdx.x;
  const int v   = bid >> 3;
  const int bh  = (bid & 7) * 4 + (v >> 5);
  const int qt  = 31 - (v & 31);
  const int q0  = qt * QT_FB;

  const float* Qbase = Qg + ((size_t)bh * T_SEQ + q0) * DK;
  const float* Kbase = Kg + (size_t)bh * T_SEQ * DK;
  const float* Vbase = Vg + (size_t)bh * T_SEQ * DV;

#pragma unroll
  for (int p = 0; p < 2; ++p) {
    int e = tid + p * 256, row = e >> 3, c4 = (e & 7) * 4;
    float4 f = *(const float4*)(Qbase + row * DK + c4);
    uint2 h, l;
    h.x = pack_hi2(f.x, f.y); h.y = pack_hi2(f.z, f.w);
    l.x = pack_hi2(f.x - trunc_bf(f.x), f.y - trunc_bf(f.y));
    l.y = pack_hi2(f.z - trunc_bf(f.z), f.w - trunc_bf(f.w));
    *(uint2*)&Qhi[row * LDSW + c4] = h;
    *(uint2*)&Qlo[row * LDSW + c4] = l;
  }
  __syncthreads();

  const int wq = wid * 16;
  const bf16x8 qhi = *(const bf16x8*)&Qhi[(wq + m) * LDSW + g * 8];
  const bf16x8 qlo = *(const bf16x8*)&Qlo[(wq + m) * LDSW + g * 8];

  f32x4 acc[4];
#pragma unroll
  for (int ct = 0; ct < 4; ++ct) acc[ct] = f32x4{0.f, 0.f, 0.f, 0.f};
  float zacc[4] = {0.f, 0.f, 0.f, 0.f};

  const int q_lane0 = q0 + wq + g * 4;
  const int q_wave_max = q0 + wq + 15;

  const int nkt = (q0 + QT_FB) / KT_FB;
  for (int kt = 0; kt < nkt; ++kt) {
    const int k0 = kt * KT_FB;
    __syncthreads();
    {
      int row = tid >> 3, c4 = (tid & 7) * 4;
      float4 f = *(const float4*)(Kbase + (size_t)(k0 + row) * DK + c4);
      uint2 h, l;
      h.x = pack_hi2(f.x, f.y); h.y = pack_hi2(f.z, f.w);
      l.x = pack_hi2(f.x - trunc_bf(f.x), f.y - trunc_bf(f.y));
      l.y = pack_hi2(f.z - trunc_bf(f.z), f.w - trunc_bf(f.w));
      *(uint2*)&Khi_[row * LDSW + c4] = h;
      *(uint2*)&Klo_[row * LDSW + c4] = l;
    }
    {
      int kk = (tid & 15) * 2, c4 = (tid >> 4) * 4;
      const float* vp = Vbase + (size_t)(k0 + kk) * DV + c4;
      float4 a = *(const float4*)vp;
      float4 b = *(const float4*)(vp + DV);
      float af[4] = {a.x, a.y, a.z, a.w};
      float bf_[4] = {b.x, b.y, b.z, b.w};
#pragma unroll
      for (int j = 0; j < 4; ++j) {
        *(unsigned*)&Vthi_[(c4 + j) * LDSW + kk] = pack_hi2(af[j], bf_[j]);
        *(unsigned*)&Vtlo_[(c4 + j) * LDSW + kk] =
            pack_hi2(af[j] - trunc_bf(af[j]), bf_[j] - trunc_bf(bf_[j]));
      }
    }
    __syncthreads();

    if (k0 > q_wave_max) continue;

#pragma unroll
    for (int k16 = 0; k16 < 2; ++k16) {
      const int kcol0 = k16 * 16;
      bf16x8 khi = *(const bf16x8*)&Khi_[(kcol0 + m) * LDSW + g * 8];
      bf16x8 klo = *(const bf16x8*)&Klo_[(kcol0 + m) * LDSW + g * 8];
      f32x4 sc = {0.f, 0.f, 0.f, 0.f};
      sc = __builtin_amdgcn_mfma_f32_16x16x32_bf16(qhi, khi, sc, 0, 0, 0);
      sc = __builtin_amdgcn_mfma_f32_16x16x32_bf16(qhi, klo, sc, 0, 0, 0);
      sc = __builtin_amdgcn_mfma_f32_16x16x32_bf16(qlo, khi, sc, 0, 0, 0);
      const int k_abs = k0 + kcol0 + m;
      const int kcol  = kcol0 + m;
#pragma unroll
      for (int r = 0; r < 4; ++r) {
        float x  = sc[r] * SCALE;
        float a3 = __builtin_fmaf(x, 0.3333333333333333f, 1.0f);
        float a2 = __builtin_fmaf(x * 0.5f, a3, 1.0f);
        float wv = __builtin_fmaf(x, a2, 1.0f);
        wv = (k_abs <= q_lane0 + r) ? wv : 0.0f;
        zacc[r] += wv;
        float wl = wv - trunc_bf(wv);
        unsigned packed = (__float_as_uint(wv) >> 16) |
                          (__float_as_uint(wl) & 0xffff0000u);
        const int q = g * 4 + r;
        Wp[wid][q * 32 + (((kcol >> 2) ^ (q & 7)) << 2) + (kcol & 3)] = packed;
      }
    }

    uint4 pa = *(const uint4*)&Wp[wid][m * 32 + (((2 * g) ^ (m & 7)) << 2)];
    uint4 pb = *(const uint4*)&Wp[wid][m * 32 + (((2 * g + 1) ^ (m & 7)) << 2)];
    union { bf16x8 v; unsigned u[4]; } WH, WL;
    WH.u[0] = (pa.x & 0xffffu) | (pa.y << 16);
    WH.u[1] = (pa.z & 0xffffu) | (pa.w << 16);
    WH.u[2] = (pb.x & 0xffffu) | (pb.y << 16);
    WH.u[3] = (pb.z & 0xffffu) | (pb.w << 16);
    WL.u[0] = (pa.x >> 16) | (pa.y & 0xffff0000u);
    WL.u[1] = (pa.z >> 16) | (pa.w & 0xffff0000u);
    WL.u[2] = (pb.x >> 16) | (pb.y & 0xffff0000u);
    WL.u[3] = (pb.z >> 16) | (pb.w & 0xffff0000u);

#pragma unroll
    for (int ct = 0; ct < 4; ++ct) {
      bf16x8 vhi = *(const bf16x8*)&Vthi_[(ct * 16 + m) * LDSW + g * 8];
      bf16x8 vlo = *(const bf16x8*)&Vtlo_[(ct * 16 + m) * LDSW + g * 8];
      acc[ct] = __builtin_amdgcn_mfma_f32_16x16x32_bf16(WH.v, vhi, acc[ct], 0, 0, 0);
      acc[ct] = __builtin_amdgcn_mfma_f32_16x16x32_bf16(WH.v, vlo, acc[ct], 0, 0, 0);
      acc[ct] = __builtin_amdgcn_mfma_f32_16x16x32_bf16(WL.v, vhi, acc[ct], 0, 0, 0);
    }
  }

  float invz[4];
#pragma unroll
  for (int r = 0; r < 4; ++r) {
    float z = zacc[r];
    z += __shfl_xor(z, 1); z += __shfl_xor(z, 2);
    z += __shfl_xor(z, 4); z += __shfl_xor(z, 8);
    invz[r] = 1.0f / z;
  }

  float* ob = Outg + ((size_t)bh * T_SEQ + (q0 + wq)) * DV;
#pragma unroll
  for (int ct = 0; ct < 4; ++ct)
#pragma unroll
    for (int r = 0; r < 4; ++r)
      ob[(g * 4 + r) * DV + ct * 16 + m] = acc[ct][r] * invz[r];
}

}  // namespace

extern "C" void kernel_launch(void* const* d_in, const int* in_sizes, int n_in,
                              void* d_out, int out_size, void* d_ws, size_t ws_size,
                              hipStream_t stream) {
  const float* Q = (const float*)d_in[0];
  const float* K = (const float*)d_in[1];
  const float* V = (const float*)d_in[2];
  float* Out = (float*)d_out;

  if (ws_size >= WS_NEED && d_ws != nullptr) {
    u16* khi  = (u16*)((char*)d_ws + KHI_OFF);
    u16* klo  = (u16*)((char*)d_ws + KLO_OFF);
    u16* vthi = (u16*)((char*)d_ws + VTHI_OFF);
    u16* vtlo = (u16*)((char*)d_ws + VTLO_OFF);

    hipLaunchKernelGGL(pack_k, dim3(2048), dim3(256), 0, stream, K, khi, klo);
    hipLaunchKernelGGL(pack_v, dim3(2048), dim3(256), 0, stream, V, vthi, vtlo);
    hipLaunchKernelGGL(taylor_attn_v3, dim3(2048), dim3(256), 0, stream,
                       Q, khi, klo, vthi, vtlo, Out);
  } else {
    hipLaunchKernelGGL(taylor_attn_fb, dim3(1024), dim3(256), 0, stream,
                       Q, K, V, Out);
  }
}

// Round 4
// 112.634 us; speedup vs baseline: 3.1473x; 1.0462x over previous
//
#include <hip/hip_runtime.h>

// Taylor attention v4: swapped-QK^T on 32x32x16 MFMA, in-register W transpose
// via v_permlane32_swap_b32 (no LDS in the K-loop), 4-way K-split per block
// with one-shot LDS combine. Pre-packed split-bf16 K / V^T in workspace.

typedef __attribute__((ext_vector_type(8))) short bf16x8;
typedef __attribute__((ext_vector_type(4))) float f32x4;
typedef __attribute__((ext_vector_type(16))) float f32x16;
typedef unsigned int u32;
typedef unsigned short u16;

namespace {

constexpr int T_SEQ = 2048;
constexpr int DK    = 32;
constexpr int DV    = 64;
constexpr int NBH   = 32;

// w = ((C3*s + C2)*s + C1)*s + 1  with s = raw dot (scale folded in; c^2 = 1/32)
constexpr float C1 = 0.17677669529663687f;   // c
constexpr float C2 = 0.015625f;              // c^2/2 (exact)
constexpr float C3 = 9.2071195e-4f;          // c^3/6

// workspace layout (bytes)
constexpr size_t KHI_OFF  = 0;
constexpr size_t KLO_OFF  = (size_t)NBH * T_SEQ * DK * 2;            //  4 MiB
constexpr size_t VTHI_OFF = KLO_OFF * 2;                             //  8 MiB
constexpr size_t VTLO_OFF = VTHI_OFF + (size_t)NBH * DV * T_SEQ * 2; // 16 MiB
constexpr size_t WS_NEED  = VTLO_OFF + (size_t)NBH * DV * T_SEQ * 2; // 24 MiB

__device__ __forceinline__ u32 pack_hi2(float f0, float f1) {
  return (__float_as_uint(f0) >> 16) | (__float_as_uint(f1) & 0xffff0000u);
}
__device__ __forceinline__ float trunc_bf(float f) {
  return __uint_as_float(__float_as_uint(f) & 0xffff0000u);
}
__device__ __forceinline__ u16 bfhi(float f) { return (u16)(__float_as_uint(f) >> 16); }

// Swap a.lanes[32:63] <-> b.lanes[0:31]; after: a = [a.lo | b.lo_old],
// b = [a.hi_old | b.hi].  One swap fills two A-frag slots for both halves.
__device__ __forceinline__ void permswap(u32& a, u32& b) {
  asm volatile("v_permlane32_swap_b32 %0, %1" : "+v"(a), "+v"(b));
}

// ---------------- pack kernel (K and V^T, split-bf16) ----------------

__global__ void pack_kv(const float* __restrict__ Kg, const float* __restrict__ Vg,
                        u16* __restrict__ Khi, u16* __restrict__ Klo,
                        u16* __restrict__ Vthi, u16* __restrict__ Vtlo) {
  __shared__ float tile[DV][33];
  const int bid = blockIdx.x;
  const int t   = threadIdx.x;
  if (bid < 2048) {  // ---- K: elementwise split
    size_t i = ((size_t)bid * 256 + t) * 4;
    float4 f = *(const float4*)(Kg + i);
    ushort4 h, l;
    h.x = bfhi(f.x); h.y = bfhi(f.y); h.z = bfhi(f.z); h.w = bfhi(f.w);
    l.x = bfhi(f.x - trunc_bf(f.x)); l.y = bfhi(f.y - trunc_bf(f.y));
    l.z = bfhi(f.z - trunc_bf(f.z)); l.w = bfhi(f.w - trunc_bf(f.w));
    *(ushort4*)(Khi + i) = h;
    *(ushort4*)(Klo + i) = l;
  } else {           // ---- V: transpose 32k x 64c tiles + split
    const int vb = bid - 2048;
    const int bh = vb >> 6;
    const int k0 = (vb & 63) * 32;
    {
      const int kl = t >> 3, c0 = (t & 7) * 8;
      const float* src = Vg + ((size_t)bh * T_SEQ + k0 + kl) * DV + c0;
      float4 a = *(const float4*)src;
      float4 b = *(const float4*)(src + 4);
      tile[c0 + 0][kl] = a.x; tile[c0 + 1][kl] = a.y;
      tile[c0 + 2][kl] = a.z; tile[c0 + 3][kl] = a.w;
      tile[c0 + 4][kl] = b.x; tile[c0 + 5][kl] = b.y;
      tile[c0 + 6][kl] = b.z; tile[c0 + 7][kl] = b.w;
    }
    __syncthreads();
    {
      const int cl = t >> 2, k8 = (t & 3) * 8;
      u32 h[4], l[4];
#pragma unroll
      for (int j = 0; j < 4; ++j) {
        float v0 = tile[cl][k8 + 2 * j];
        float v1 = tile[cl][k8 + 2 * j + 1];
        h[j] = pack_hi2(v0, v1);
        l[j] = pack_hi2(v0 - trunc_bf(v0), v1 - trunc_bf(v1));
      }
      size_t off = ((size_t)(bh * DV + cl)) * T_SEQ + k0 + k8;
      *(uint4*)(Vthi + off) = make_uint4(h[0], h[1], h[2], h[3]);
      *(uint4*)(Vtlo + off) = make_uint4(l[0], l[1], l[2], l[3]);
    }
  }
}

// ---------------- main kernel (v4) ----------------

__global__ __launch_bounds__(256, 4)
void taylor_attn_v4(const float* __restrict__ Qg, const u16* __restrict__ Khi,
                    const u16* __restrict__ Klo, const u16* __restrict__ Vthi,
                    const u16* __restrict__ Vtlo, float* __restrict__ Outg) {
  __shared__ __align__(16) float Comb[4 * 2048];   // 32 KB: 4 waves x 32q x 64c
  __shared__ float Zs[4 * 32];

  const int tid = threadIdx.x;
  const int l   = tid & 63;
  const int w   = tid >> 6;
  const int cq  = l & 31;    // q (scores/PV N/M row), c col owner in D
  const int hi  = l >> 5;    // lane half

  // decode: 8 XCDs x 4 bh x 64 strips (descending: heavy first)
  const int bid = blockIdx.x;
  const int xcd = bid & 7;
  const int u   = bid >> 3;
  const int bh  = xcd * 4 + (u >> 6);
  const int s   = 63 - (u & 63);
  const int q0  = s * 32;

  const int steps = s + 1;
  const int cch   = (steps + 3) >> 2;
  const int kt0   = w * cch;
  const int kt1   = min(kt0 + cch, steps);

  // ---- Q B-fragments (col=q=cq, d = t*16 + hi*8 + j), packed hi/lo
  bf16x8 qfh[2], qfl[2];
#pragma unroll
  for (int t = 0; t < 2; ++t) {
    const float* qp = Qg + ((size_t)bh * T_SEQ + q0 + cq) * DK + t * 16 + hi * 8;
    float4 a = *(const float4*)qp;
    float4 b = *(const float4*)(qp + 4);
    union { bf16x8 v; u32 u[4]; } H, L;
    H.u[0] = pack_hi2(a.x, a.y); H.u[1] = pack_hi2(a.z, a.w);
    H.u[2] = pack_hi2(b.x, b.y); H.u[3] = pack_hi2(b.z, b.w);
    L.u[0] = pack_hi2(a.x - trunc_bf(a.x), a.y - trunc_bf(a.y));
    L.u[1] = pack_hi2(a.z - trunc_bf(a.z), a.w - trunc_bf(a.w));
    L.u[2] = pack_hi2(b.x - trunc_bf(b.x), b.y - trunc_bf(b.y));
    L.u[3] = pack_hi2(b.z - trunc_bf(b.z), b.w - trunc_bf(b.w));
    qfh[t] = H.v; qfl[t] = L.v;
  }

  f32x16 acc[2];
#pragma unroll
  for (int ct = 0; ct < 2; ++ct)
#pragma unroll
    for (int r = 0; r < 16; ++r) acc[ct][r] = 0.f;
  float zacc = 0.f;

  const u16* kbh_hi = Khi + (size_t)bh * T_SEQ * DK;
  const u16* kbh_lo = Klo + (size_t)bh * T_SEQ * DK;
  const u16* vbh_hi = Vthi + (size_t)bh * DV * T_SEQ;
  const u16* vbh_lo = Vtlo + (size_t)bh * DV * T_SEQ;

  for (int kt = kt0; kt < kt1; ++kt) {
    const int k0 = kt * 32;

    // ---- K A-fragments (row=k=cq, d = t*16 + hi*8 + j), L2-hot global
    bf16x8 kfh[2], kfl[2];
#pragma unroll
    for (int t = 0; t < 2; ++t) {
      size_t off = (size_t)(k0 + cq) * DK + t * 16 + hi * 8;
      kfh[t] = *(const bf16x8*)(kbh_hi + off);
      kfl[t] = *(const bf16x8*)(kbh_lo + off);
    }

    // ---- swapped scores: D = K.Q^T -> col=q=cq, row k=(r&3)+8*(r>>2)+4*hi
    f32x16 d;
#pragma unroll
    for (int r = 0; r < 16; ++r) d[r] = 0.f;
    d = __builtin_amdgcn_mfma_f32_32x32x16_bf16(kfh[0], qfh[0], d, 0, 0, 0);
    d = __builtin_amdgcn_mfma_f32_32x32x16_bf16(kfh[0], qfl[0], d, 0, 0, 0);
    d = __builtin_amdgcn_mfma_f32_32x32x16_bf16(kfl[0], qfh[0], d, 0, 0, 0);
    d = __builtin_amdgcn_mfma_f32_32x32x16_bf16(kfh[1], qfh[1], d, 0, 0, 0);
    d = __builtin_amdgcn_mfma_f32_32x32x16_bf16(kfh[1], qfl[1], d, 0, 0, 0);
    d = __builtin_amdgcn_mfma_f32_32x32x16_bf16(kfl[1], qfh[1], d, 0, 0, 0);

    // ---- poly (+ causal mask on the diagonal step), Z
    float wv[16];
    if (kt == s) {
#pragma unroll
      for (int r = 0; r < 16; ++r) {
        float sc = d[r];
        float t_ = __builtin_fmaf(sc, C3, C2);
        t_       = __builtin_fmaf(sc, t_, C1);
        float wr = __builtin_fmaf(sc, t_, 1.0f);
        const int krel = (r & 3) + 8 * (r >> 2) + 4 * hi;
        wr = (krel <= cq) ? wr : 0.f;
        zacc += wr;
        wv[r] = wr;
      }
    } else {
#pragma unroll
      for (int r = 0; r < 16; ++r) {
        float sc = d[r];
        float t_ = __builtin_fmaf(sc, C3, C2);
        t_       = __builtin_fmaf(sc, t_, C1);
        float wr = __builtin_fmaf(sc, t_, 1.0f);
        zacc += wr;
        wv[r] = wr;
      }
    }

    // ---- in-register W transpose -> PV A-frags (hi and lo), via permlane swaps
    union { bf16x8 v; u32 u[4]; } WH[2], WL[2];
#pragma unroll
    for (int t = 0; t < 2; ++t) {
      const int b = t * 8;
      u32 p0 = pack_hi2(wv[b + 0], wv[b + 1]);
      u32 p1 = pack_hi2(wv[b + 2], wv[b + 3]);
      u32 p2 = pack_hi2(wv[b + 4], wv[b + 5]);
      u32 p3 = pack_hi2(wv[b + 6], wv[b + 7]);
      u32 r0 = pack_hi2(wv[b + 0] - trunc_bf(wv[b + 0]), wv[b + 1] - trunc_bf(wv[b + 1]));
      u32 r1 = pack_hi2(wv[b + 2] - trunc_bf(wv[b + 2]), wv[b + 3] - trunc_bf(wv[b + 3]));
      u32 r2 = pack_hi2(wv[b + 4] - trunc_bf(wv[b + 4]), wv[b + 5] - trunc_bf(wv[b + 5]));
      u32 r3 = pack_hi2(wv[b + 6] - trunc_bf(wv[b + 6]), wv[b + 7] - trunc_bf(wv[b + 7]));
      permswap(p0, p2); permswap(p1, p3);
      permswap(r0, r2); permswap(r1, r3);
      WH[t].u[0] = p0; WH[t].u[1] = p1; WH[t].u[2] = p2; WH[t].u[3] = p3;
      WL[t].u[0] = r0; WL[t].u[1] = r1; WL[t].u[2] = r2; WL[t].u[3] = r3;
    }

    // ---- PV: acc[ct] += W * V  (B-frag col=c=cq, k = t*16 + hi*8 + j)
#pragma unroll
    for (int ct = 0; ct < 2; ++ct) {
#pragma unroll
      for (int t = 0; t < 2; ++t) {
        size_t voff = (size_t)(ct * 32 + cq) * T_SEQ + k0 + t * 16 + hi * 8;
        bf16x8 vh = *(const bf16x8*)(vbh_hi + voff);
        bf16x8 vl = *(const bf16x8*)(vbh_lo + voff);
        acc[ct] = __builtin_amdgcn_mfma_f32_32x32x16_bf16(WH[t].v, vh, acc[ct], 0, 0, 0);
        acc[ct] = __builtin_amdgcn_mfma_f32_32x32x16_bf16(WH[t].v, vl, acc[ct], 0, 0, 0);
        acc[ct] = __builtin_amdgcn_mfma_f32_32x32x16_bf16(WL[t].v, vh, acc[ct], 0, 0, 0);
      }
    }
  }

  // ---- Z: fold lane halves (lane l and l^32 share q=cq), publish per wave
  {
    float zt = zacc + __shfl_xor(zacc, 32);
    if (hi == 0) Zs[w * 32 + cq] = zt;
  }

  // ---- publish partial O: row q_rel=(r&3)+8*(r>>2)+4*hi, col = ct*32+cq
#pragma unroll
  for (int ct = 0; ct < 2; ++ct)
#pragma unroll
    for (int r = 0; r < 16; ++r) {
      const int qr = (r & 3) + 8 * (r >> 2) + 4 * hi;
      Comb[w * 2048 + qr * 64 + ct * 32 + cq] = acc[ct][r];
    }

  __syncthreads();

  // ---- combine 4 wave partials, divide by Z, store
  const f32x4* C4 = (const f32x4*)Comb;
#pragma unroll
  for (int i = 0; i < 2; ++i) {
    const int e4  = tid + i * 256;        // 0..511 float4s of the 32x64 tile
    const int row = e4 >> 4;
    f32x4 ssum = C4[e4] + C4[512 + e4] + C4[1024 + e4] + C4[1536 + e4];
    float z = Zs[row] + Zs[32 + row] + Zs[64 + row] + Zs[96 + row];
    float inv = 1.0f / z;
    float4 o;
    o.x = ssum[0] * inv; o.y = ssum[1] * inv;
    o.z = ssum[2] * inv; o.w = ssum[3] * inv;
    *(float4*)(Outg + ((size_t)bh * T_SEQ + q0 + row) * DV + (e4 & 15) * 4) = o;
  }
}

// ---------------- fallback (no workspace): v2 staged-LDS kernel ----------------

constexpr int QT_FB = 64;
constexpr int KT_FB = 32;
constexpr int LDSW  = 40;
constexpr float SCALE = 0.17677669529663687f;

__global__ __launch_bounds__(256, 4)
void taylor_attn_fb(const float* __restrict__ Qg, const float* __restrict__ Kg,
                    const float* __restrict__ Vg, float* __restrict__ Outg) {
  __shared__ __align__(16) unsigned short Qhi[QT_FB * LDSW], Qlo[QT_FB * LDSW];
  __shared__ __align__(16) unsigned short Khi_[KT_FB * LDSW], Klo_[KT_FB * LDSW];
  __shared__ __align__(16) unsigned short Vthi_[DV * LDSW], Vtlo_[DV * LDSW];
  __shared__ __align__(16) unsigned Wp[4][16 * 32];

  const int tid  = threadIdx.x;
  const int lane = tid & 63;
  const int wid  = tid >> 6;
  const int m    = lane & 15;
  const int g    = lane >> 4;

  const int bid = blockIdx.x;
  const int v   = bid >> 3;
  const int bh  = (bid & 7) * 4 + (v >> 5);
  const int qt  = 31 - (v & 31);
  const int q0  = qt * QT_FB;

  const float* Qbase = Qg + ((size_t)bh * T_SEQ + q0) * DK;
  const float* Kbase = Kg + (size_t)bh * T_SEQ * DK;
  const float* Vbase = Vg + (size_t)bh * T_SEQ * DV;

#pragma unroll
  for (int p = 0; p < 2; ++p) {
    int e = tid + p * 256, row = e >> 3, c4 = (e & 7) * 4;
    float4 f = *(const float4*)(Qbase + row * DK + c4);
    uint2 h, l;
    h.x = pack_hi2(f.x, f.y); h.y = pack_hi2(f.z, f.w);
    l.x = pack_hi2(f.x - trunc_bf(f.x), f.y - trunc_bf(f.y));
    l.y = pack_hi2(f.z - trunc_bf(f.z), f.w - trunc_bf(f.w));
    *(uint2*)&Qhi[row * LDSW + c4] = h;
    *(uint2*)&Qlo[row * LDSW + c4] = l;
  }
  __syncthreads();

  const int wq = wid * 16;
  const bf16x8 qhi = *(const bf16x8*)&Qhi[(wq + m) * LDSW + g * 8];
  const bf16x8 qlo = *(const bf16x8*)&Qlo[(wq + m) * LDSW + g * 8];

  f32x4 acc[4];
#pragma unroll
  for (int ct = 0; ct < 4; ++ct) acc[ct] = f32x4{0.f, 0.f, 0.f, 0.f};
  float zacc[4] = {0.f, 0.f, 0.f, 0.f};

  const int q_lane0 = q0 + wq + g * 4;
  const int q_wave_max = q0 + wq + 15;

  const int nkt = (q0 + QT_FB) / KT_FB;
  for (int kt = 0; kt < nkt; ++kt) {
    const int k0 = kt * KT_FB;
    __syncthreads();
    {
      int row = tid >> 3, c4 = (tid & 7) * 4;
      float4 f = *(const float4*)(Kbase + (size_t)(k0 + row) * DK + c4);
      uint2 h, l;
      h.x = pack_hi2(f.x, f.y); h.y = pack_hi2(f.z, f.w);
      l.x = pack_hi2(f.x - trunc_bf(f.x), f.y - trunc_bf(f.y));
      l.y = pack_hi2(f.z - trunc_bf(f.z), f.w - trunc_bf(f.w));
      *(uint2*)&Khi_[row * LDSW + c4] = h;
      *(uint2*)&Klo_[row * LDSW + c4] = l;
    }
    {
      int kk = (tid & 15) * 2, c4 = (tid >> 4) * 4;
      const float* vp = Vbase + (size_t)(k0 + kk) * DV + c4;
      float4 a = *(const float4*)vp;
      float4 b = *(const float4*)(vp + DV);
      float af[4] = {a.x, a.y, a.z, a.w};
      float bf_[4] = {b.x, b.y, b.z, b.w};
#pragma unroll
      for (int j = 0; j < 4; ++j) {
        *(unsigned*)&Vthi_[(c4 + j) * LDSW + kk] = pack_hi2(af[j], bf_[j]);
        *(unsigned*)&Vtlo_[(c4 + j) * LDSW + kk] =
            pack_hi2(af[j] - trunc_bf(af[j]), bf_[j] - trunc_bf(bf_[j]));
      }
    }
    __syncthreads();

    if (k0 > q_wave_max) continue;

#pragma unroll
    for (int k16 = 0; k16 < 2; ++k16) {
      const int kcol0 = k16 * 16;
      bf16x8 khi = *(const bf16x8*)&Khi_[(kcol0 + m) * LDSW + g * 8];
      bf16x8 klo = *(const bf16x8*)&Klo_[(kcol0 + m) * LDSW + g * 8];
      f32x4 sc = {0.f, 0.f, 0.f, 0.f};
      sc = __builtin_amdgcn_mfma_f32_16x16x32_bf16(qhi, khi, sc, 0, 0, 0);
      sc = __builtin_amdgcn_mfma_f32_16x16x32_bf16(qhi, klo, sc, 0, 0, 0);
      sc = __builtin_amdgcn_mfma_f32_16x16x32_bf16(qlo, khi, sc, 0, 0, 0);
      const int k_abs = k0 + kcol0 + m;
      const int kcol  = kcol0 + m;
#pragma unroll
      for (int r = 0; r < 4; ++r) {
        float x  = sc[r] * SCALE;
        float a3 = __builtin_fmaf(x, 0.3333333333333333f, 1.0f);
        float a2 = __builtin_fmaf(x * 0.5f, a3, 1.0f);
        float wv = __builtin_fmaf(x, a2, 1.0f);
        wv = (k_abs <= q_lane0 + r) ? wv : 0.0f;
        zacc[r] += wv;
        float wl = wv - trunc_bf(wv);
        unsigned packed = (__float_as_uint(wv) >> 16) |
                          (__float_as_uint(wl) & 0xffff0000u);
        const int q = g * 4 + r;
        Wp[wid][q * 32 + (((kcol >> 2) ^ (q & 7)) << 2) + (kcol & 3)] = packed;
      }
    }

    uint4 pa = *(const uint4*)&Wp[wid][m * 32 + (((2 * g) ^ (m & 7)) << 2)];
    uint4 pb = *(const uint4*)&Wp[wid][m * 32 + (((2 * g + 1) ^ (m & 7)) << 2)];
    union { bf16x8 v; unsigned u[4]; } WH, WL;
    WH.u[0] = (pa.x & 0xffffu) | (pa.y << 16);
    WH.u[1] = (pa.z & 0xffffu) | (pa.w << 16);
    WH.u[2] = (pb.x & 0xffffu) | (pb.y << 16);
    WH.u[3] = (pb.z & 0xffffu) | (pb.w << 16);
    WL.u[0] = (pa.x >> 16) | (pa.y & 0xffff0000u);
    WL.u[1] = (pa.z >> 16) | (pa.w & 0xffff0000u);
    WL.u[2] = (pb.x >> 16) | (pb.y & 0xffff0000u);
    WL.u[3] = (pb.z >> 16) | (pb.w & 0xffff0000u);

#pragma unroll
    for (int ct = 0; ct < 4; ++ct) {
      bf16x8 vhi = *(const bf16x8*)&Vthi_[(ct * 16 + m) * LDSW + g * 8];
      bf16x8 vlo = *(const bf16x8*)&Vtlo_[(ct * 16 + m) * LDSW + g * 8];
      acc[ct] = __builtin_amdgcn_mfma_f32_16x16x32_bf16(WH.v, vhi, acc[ct], 0, 0, 0);
      acc[ct] = __builtin_amdgcn_mfma_f32_16x16x32_bf16(WH.v, vlo, acc[ct], 0, 0, 0);
      acc[ct] = __builtin_amdgcn_mfma_f32_16x16x32_bf16(WL.v, vhi, acc[ct], 0, 0, 0);
    }
  }

  float invz[4];
#pragma unroll
  for (int r = 0; r < 4; ++r) {
    float z = zacc[r];
    z += __shfl_xor(z, 1); z += __shfl_xor(z, 2);
    z += __shfl_xor(z, 4); z += __shfl_xor(z, 8);
    invz[r] = 1.0f / z;
  }

  float* ob = Outg + ((size_t)bh * T_SEQ + (q0 + wq)) * DV;
#pragma unroll
  for (int ct = 0; ct < 4; ++ct)
#pragma unroll
    for (int r = 0; r < 4; ++r)
      ob[(g * 4 + r) * DV + ct * 16 + m] = acc[ct][r] * invz[r];
}

}  // namespace

extern "C" void kernel_launch(void* const* d_in, const int* in_sizes, int n_in,
                              void* d_out, int out_size, void* d_ws, size_t ws_size,
                              hipStream_t stream) {
  const float* Q = (const float*)d_in[0];
  const float* K = (const float*)d_in[1];
  const float* V = (const float*)d_in[2];
  float* Out = (float*)d_out;

  if (ws_size >= WS_NEED && d_ws != nullptr) {
    u16* khi  = (u16*)((char*)d_ws + KHI_OFF);
    u16* klo  = (u16*)((char*)d_ws + KLO_OFF);
    u16* vthi = (u16*)((char*)d_ws + VTHI_OFF);
    u16* vtlo = (u16*)((char*)d_ws + VTLO_OFF);

    hipLaunchKernelGGL(pack_kv, dim3(4096), dim3(256), 0, stream,
                       K, V, khi, klo, vthi, vtlo);
    hipLaunchKernelGGL(taylor_attn_v4, dim3(2048), dim3(256), 0, stream,
                       Q, khi, klo, vthi, vtlo, Out);
  } else {
    hipLaunchKernelGGL(taylor_attn_fb, dim3(1024), dim3(256), 0, stream,
                       Q, K, V, Out);
  }
}

// Round 5
// 68.193 us; speedup vs baseline: 5.1983x; 1.6517x over previous
//
#include <hip/hip_runtime.h>
#include <hip/hip_bf16.h>

// Taylor attention v5: 2-wave blocks, one (bh,strip) per block, exact static
// per-CU balance (strip pairing 2c / 63-2c), all 2048 blocks co-resident at
// 16 waves/CU. Swapped-QK^T 32x32x16 MFMA with full split-bf16 scores;
// PV uses RNE-bf16 W and V (error analysis: ~2^-9 rel, ~1e-3 on out).
// In-register W transpose via v_permlane32_swap_b32; LDS only for the
// 2-wave combine (8.4 KB).

typedef __attribute__((ext_vector_type(8))) short bf16x8;
typedef __attribute__((ext_vector_type(16))) float f32x16;
typedef unsigned int u32;
typedef unsigned short u16;

namespace {

constexpr int T_SEQ = 2048;
constexpr int DK    = 32;
constexpr int DV    = 64;
constexpr int NBH   = 32;

// w = ((C3*s + C2)*s + C1)*s + 1  with s = raw dot (1/sqrt(32) folded in)
constexpr float C1 = 0.17677669529663687f;   // c
constexpr float C2 = 0.015625f;              // c^2/2 (exact)
constexpr float C3 = 9.2071195e-4f;          // c^3/6

// workspace layout (bytes): Khi 4MiB | Klo 4MiB | Vthi 8MiB
constexpr size_t KHI_OFF  = 0;
constexpr size_t KLO_OFF  = (size_t)NBH * T_SEQ * DK * 2;             //  4 MiB
constexpr size_t VTHI_OFF = KLO_OFF * 2;                              //  8 MiB
constexpr size_t WS_NEED  = VTHI_OFF + (size_t)NBH * DV * T_SEQ * 2;  // 16 MiB

__device__ __forceinline__ u32 pack_hi2(float f0, float f1) {
  return (__float_as_uint(f0) >> 16) | (__float_as_uint(f1) & 0xffff0000u);
}
__device__ __forceinline__ float trunc_bf(float f) {
  return __uint_as_float(__float_as_uint(f) & 0xffff0000u);
}
__device__ __forceinline__ u16 bfhi(float f) { return (u16)(__float_as_uint(f) >> 16); }

// RNE bf16 pair pack (compiler lowers the casts to v_cvt_pk_bf16_f32)
__device__ __forceinline__ u32 pack_rn2(float f0, float f1) {
  union { __hip_bfloat16 h; u16 u; } a, b;
  a.h = __hip_bfloat16(f0);
  b.h = __hip_bfloat16(f1);
  return (u32)a.u | ((u32)b.u << 16);
}

// Swap a.lanes[32:63] <-> b.lanes[0:31].
__device__ __forceinline__ void permswap(u32& a, u32& b) {
  asm volatile("v_permlane32_swap_b32 %0, %1" : "+v"(a), "+v"(b));
}

// ---------------- pack kernel (K split-bf16; V^T RNE-bf16) ----------------

__global__ void pack_kv(const float* __restrict__ Kg, const float* __restrict__ Vg,
                        u16* __restrict__ Khi, u16* __restrict__ Klo,
                        u16* __restrict__ Vthi) {
  __shared__ float tile[DV][33];
  const int bid = blockIdx.x;
  const int t   = threadIdx.x;
  if (bid < 2048) {  // ---- K: elementwise split (truncation hi + residual lo)
    size_t i = ((size_t)bid * 256 + t) * 4;
    float4 f = *(const float4*)(Kg + i);
    ushort4 h, l;
    h.x = bfhi(f.x); h.y = bfhi(f.y); h.z = bfhi(f.z); h.w = bfhi(f.w);
    l.x = bfhi(f.x - trunc_bf(f.x)); l.y = bfhi(f.y - trunc_bf(f.y));
    l.z = bfhi(f.z - trunc_bf(f.z)); l.w = bfhi(f.w - trunc_bf(f.w));
    *(ushort4*)(Khi + i) = h;
    *(ushort4*)(Klo + i) = l;
  } else {           // ---- V: transpose 32k x 64c tiles, RNE hi only
    const int vb = bid - 2048;
    const int bh = vb >> 6;
    const int k0 = (vb & 63) * 32;
    {
      const int kl = t >> 3, c0 = (t & 7) * 8;
      const float* src = Vg + ((size_t)bh * T_SEQ + k0 + kl) * DV + c0;
      float4 a = *(const float4*)src;
      float4 b = *(const float4*)(src + 4);
      tile[c0 + 0][kl] = a.x; tile[c0 + 1][kl] = a.y;
      tile[c0 + 2][kl] = a.z; tile[c0 + 3][kl] = a.w;
      tile[c0 + 4][kl] = b.x; tile[c0 + 5][kl] = b.y;
      tile[c0 + 6][kl] = b.z; tile[c0 + 7][kl] = b.w;
    }
    __syncthreads();
    {
      const int cl = t >> 2, k8 = (t & 3) * 8;
      u32 h[4];
#pragma unroll
      for (int j = 0; j < 4; ++j)
        h[j] = pack_rn2(tile[cl][k8 + 2 * j], tile[cl][k8 + 2 * j + 1]);
      size_t off = ((size_t)(bh * DV + cl)) * T_SEQ + k0 + k8;
      *(uint4*)(Vthi + off) = make_uint4(h[0], h[1], h[2], h[3]);
    }
  }
}

// ---------------- main kernel (v5) ----------------

__global__ __launch_bounds__(128, 4)
void taylor_attn_v5(const float* __restrict__ Qg, const u16* __restrict__ Khi,
                    const u16* __restrict__ Klo, const u16* __restrict__ Vthi,
                    float* __restrict__ Outg) {
  __shared__ __align__(16) float Sp[32 * 64];  // wave1 partial S (8 KB)
  __shared__ float Zp[64];                     // 2 waves x 32 q

  const int tid = threadIdx.x;
  const int l   = tid & 63;
  const int w   = tid >> 6;
  const int cq  = l & 31;
  const int hi  = l >> 5;

  // decode: per-CU exact balance. xcd = bid&7 -> 4 bh per XCD (L2-resident);
  // c = CU slot, j>=4 pairs strip 63-2c with j<4's strip 2c (65 steps/pair).
  const int bid = blockIdx.x;
  const int xcd = bid & 7;
  const int u   = bid >> 3;
  const int j   = u >> 5;       // 0..7
  const int c   = u & 31;       // 0..31
  const int bh  = xcd * 4 + (j & 3);
  const int s   = (j >= 4) ? (63 - 2 * c) : (2 * c);
  const int q0  = s * 32;

  const int nsteps = s + 1;
  const int half   = (nsteps + 1) >> 1;
  const int kt0    = w ? half : 0;
  const int kt1    = w ? nsteps : half;

  // ---- Q B-fragments (full split: trunc hi + residual lo)
  bf16x8 qfh[2], qfl[2];
#pragma unroll
  for (int t = 0; t < 2; ++t) {
    const float* qp = Qg + ((size_t)bh * T_SEQ + q0 + cq) * DK + t * 16 + hi * 8;
    float4 a = *(const float4*)qp;
    float4 b = *(const float4*)(qp + 4);
    union { bf16x8 v; u32 u[4]; } H, L;
    H.u[0] = pack_hi2(a.x, a.y); H.u[1] = pack_hi2(a.z, a.w);
    H.u[2] = pack_hi2(b.x, b.y); H.u[3] = pack_hi2(b.z, b.w);
    L.u[0] = pack_hi2(a.x - trunc_bf(a.x), a.y - trunc_bf(a.y));
    L.u[1] = pack_hi2(a.z - trunc_bf(a.z), a.w - trunc_bf(a.w));
    L.u[2] = pack_hi2(b.x - trunc_bf(b.x), b.y - trunc_bf(b.y));
    L.u[3] = pack_hi2(b.z - trunc_bf(b.z), b.w - trunc_bf(b.w));
    qfh[t] = H.v; qfl[t] = L.v;
  }

  f32x16 acc[2];
#pragma unroll
  for (int ct = 0; ct < 2; ++ct)
#pragma unroll
    for (int r = 0; r < 16; ++r) acc[ct][r] = 0.f;
  float zacc = 0.f;

  const u16* kbh_hi = Khi + (size_t)bh * T_SEQ * DK;
  const u16* kbh_lo = Klo + (size_t)bh * T_SEQ * DK;
  const u16* vbh_hi = Vthi + (size_t)bh * DV * T_SEQ;

  for (int kt = kt0; kt < kt1; ++kt) {
    const int k0 = kt * 32;

    // ---- K A-fragments (L2-hot)
    bf16x8 kfh[2], kfl[2];
#pragma unroll
    for (int t = 0; t < 2; ++t) {
      size_t off = (size_t)(k0 + cq) * DK + t * 16 + hi * 8;
      kfh[t] = *(const bf16x8*)(kbh_hi + off);
      kfl[t] = *(const bf16x8*)(kbh_lo + off);
    }

    // ---- swapped scores, two parallel 3-chains then merge
    f32x16 d0, d1;
#pragma unroll
    for (int r = 0; r < 16; ++r) { d0[r] = 0.f; d1[r] = 0.f; }
    d0 = __builtin_amdgcn_mfma_f32_32x32x16_bf16(kfh[0], qfh[0], d0, 0, 0, 0);
    d1 = __builtin_amdgcn_mfma_f32_32x32x16_bf16(kfh[1], qfh[1], d1, 0, 0, 0);
    d0 = __builtin_amdgcn_mfma_f32_32x32x16_bf16(kfh[0], qfl[0], d0, 0, 0, 0);
    d1 = __builtin_amdgcn_mfma_f32_32x32x16_bf16(kfh[1], qfl[1], d1, 0, 0, 0);
    d0 = __builtin_amdgcn_mfma_f32_32x32x16_bf16(kfl[0], qfh[0], d0, 0, 0, 0);
    d1 = __builtin_amdgcn_mfma_f32_32x32x16_bf16(kfl[1], qfh[1], d1, 0, 0, 0);

    // ---- poly + (diagonal) mask + Z
    float wv[16];
    const bool diag = (kt == s);
#pragma unroll
    for (int r = 0; r < 16; ++r) {
      float sc = d0[r] + d1[r];
      float t_ = __builtin_fmaf(sc, C3, C2);
      t_       = __builtin_fmaf(sc, t_, C1);
      float wr = __builtin_fmaf(sc, t_, 1.0f);
      if (diag) {
        const int krel = (r & 3) + 8 * (r >> 2) + 4 * hi;
        wr = (krel <= cq) ? wr : 0.f;
      }
      zacc += wr;
      wv[r] = wr;
    }

    // ---- W -> RNE bf16, in-register transpose to PV A-frags
    union { bf16x8 v; u32 u[4]; } WH[2];
#pragma unroll
    for (int t = 0; t < 2; ++t) {
      const int b = t * 8;
      u32 p0 = pack_rn2(wv[b + 0], wv[b + 1]);
      u32 p1 = pack_rn2(wv[b + 2], wv[b + 3]);
      u32 p2 = pack_rn2(wv[b + 4], wv[b + 5]);
      u32 p3 = pack_rn2(wv[b + 6], wv[b + 7]);
      permswap(p0, p2); permswap(p1, p3);
      WH[t].u[0] = p0; WH[t].u[1] = p1; WH[t].u[2] = p2; WH[t].u[3] = p3;
    }

    // ---- PV: 4 MFMAs (RNE V, no lo terms)
#pragma unroll
    for (int ct = 0; ct < 2; ++ct) {
#pragma unroll
      for (int t = 0; t < 2; ++t) {
        size_t voff = (size_t)(ct * 32 + cq) * T_SEQ + k0 + t * 16 + hi * 8;
        bf16x8 vh = *(const bf16x8*)(vbh_hi + voff);
        acc[ct] = __builtin_amdgcn_mfma_f32_32x32x16_bf16(WH[t].v, vh, acc[ct], 0, 0, 0);
      }
    }
  }

  // ---- Z fold + publish
  {
    float zt = zacc + __shfl_xor(zacc, 32);
    if (hi == 0) Zp[w * 32 + cq] = zt;
  }
  // ---- wave1 publishes its S partial
  if (w == 1) {
#pragma unroll
    for (int ct = 0; ct < 2; ++ct)
#pragma unroll
      for (int r = 0; r < 16; ++r) {
        const int qr = (r & 3) + 8 * (r >> 2) + 4 * hi;
        Sp[qr * 64 + ct * 32 + cq] = acc[ct][r];
      }
  }
  __syncthreads();

  // ---- wave0 combines + stores
  if (w == 0) {
    float zinv[16];
#pragma unroll
    for (int r = 0; r < 16; ++r) {
      const int qr = (r & 3) + 8 * (r >> 2) + 4 * hi;
      zinv[r] = 1.0f / (Zp[qr] + Zp[32 + qr]);
    }
#pragma unroll
    for (int ct = 0; ct < 2; ++ct)
#pragma unroll
      for (int r = 0; r < 16; ++r) {
        const int qr = (r & 3) + 8 * (r >> 2) + 4 * hi;
        float o = (acc[ct][r] + Sp[qr * 64 + ct * 32 + cq]) * zinv[r];
        Outg[((size_t)bh * T_SEQ + q0 + qr) * DV + ct * 32 + cq] = o;
      }
  }
}

// ---------------- fallback (no workspace): v2 staged-LDS kernel ----------------

constexpr int QT_FB = 64;
constexpr int KT_FB = 32;
constexpr int LDSW  = 40;
constexpr float SCALE = 0.17677669529663687f;

__global__ __launch_bounds__(256, 4)
void taylor_attn_fb(const float* __restrict__ Qg, const float* __restrict__ Kg,
                    const float* __restrict__ Vg, float* __restrict__ Outg) {
  __shared__ __align__(16) unsigned short Qhi[QT_FB * LDSW], Qlo[QT_FB * LDSW];
  __shared__ __align__(16) unsigned short Khi_[KT_FB * LDSW], Klo_[KT_FB * LDSW];
  __shared__ __align__(16) unsigned short Vthi_[DV * LDSW], Vtlo_[DV * LDSW];
  __shared__ __align__(16) unsigned Wp[4][16 * 32];

  const int tid  = threadIdx.x;
  const int lane = tid & 63;
  const int wid  = tid >> 6;
  const int m    = lane & 15;
  const int g    = lane >> 4;

  const int bid = blockIdx.x;
  const int v   = bid >> 3;
  const int bh  = (bid & 7) * 4 + (v >> 5);
  const int qt  = 31 - (v & 31);
  const int q0  = qt * QT_FB;

  const float* Qbase = Qg + ((size_t)bh * T_SEQ + q0) * DK;
  const float* Kbase = Kg + (size_t)bh * T_SEQ * DK;
  const float* Vbase = Vg + (size_t)bh * T_SEQ * DV;

#pragma unroll
  for (int p = 0; p < 2; ++p) {
    int e = tid + p * 256, row = e >> 3, c4 = (e & 7) * 4;
    float4 f = *(const float4*)(Qbase + row * DK + c4);
    uint2 h, l;
    h.x = pack_hi2(f.x, f.y); h.y = pack_hi2(f.z, f.w);
    l.x = pack_hi2(f.x - trunc_bf(f.x), f.y - trunc_bf(f.y));
    l.y = pack_hi2(f.z - trunc_bf(f.z), f.w - trunc_bf(f.w));
    *(uint2*)&Qhi[row * LDSW + c4] = h;
    *(uint2*)&Qlo[row * LDSW + c4] = l;
  }
  __syncthreads();

  const int wq = wid * 16;
  const bf16x8 qhi = *(const bf16x8*)&Qhi[(wq + m) * LDSW + g * 8];
  const bf16x8 qlo = *(const bf16x8*)&Qlo[(wq + m) * LDSW + g * 8];

  typedef __attribute__((ext_vector_type(4))) float f32x4;
  f32x4 acc[4];
#pragma unroll
  for (int ct = 0; ct < 4; ++ct) acc[ct] = f32x4{0.f, 0.f, 0.f, 0.f};
  float zacc[4] = {0.f, 0.f, 0.f, 0.f};

  const int q_lane0 = q0 + wq + g * 4;
  const int q_wave_max = q0 + wq + 15;

  const int nkt = (q0 + QT_FB) / KT_FB;
  for (int kt = 0; kt < nkt; ++kt) {
    const int k0 = kt * KT_FB;
    __syncthreads();
    {
      int row = tid >> 3, c4 = (tid & 7) * 4;
      float4 f = *(const float4*)(Kbase + (size_t)(k0 + row) * DK + c4);
      uint2 h, l;
      h.x = pack_hi2(f.x, f.y); h.y = pack_hi2(f.z, f.w);
      l.x = pack_hi2(f.x - trunc_bf(f.x), f.y - trunc_bf(f.y));
      l.y = pack_hi2(f.z - trunc_bf(f.z), f.w - trunc_bf(f.w));
      *(uint2*)&Khi_[row * LDSW + c4] = h;
      *(uint2*)&Klo_[row * LDSW + c4] = l;
    }
    {
      int kk = (tid & 15) * 2, c4 = (tid >> 4) * 4;
      const float* vp = Vbase + (size_t)(k0 + kk) * DV + c4;
      float4 a = *(const float4*)vp;
      float4 b = *(const float4*)(vp + DV);
      float af[4] = {a.x, a.y, a.z, a.w};
      float bf_[4] = {b.x, b.y, b.z, b.w};
#pragma unroll
      for (int jj = 0; jj < 4; ++jj) {
        *(unsigned*)&Vthi_[(c4 + jj) * LDSW + kk] = pack_hi2(af[jj], bf_[jj]);
        *(unsigned*)&Vtlo_[(c4 + jj) * LDSW + kk] =
            pack_hi2(af[jj] - trunc_bf(af[jj]), bf_[jj] - trunc_bf(bf_[jj]));
      }
    }
    __syncthreads();

    if (k0 > q_wave_max) continue;

#pragma unroll
    for (int k16 = 0; k16 < 2; ++k16) {
      const int kcol0 = k16 * 16;
      bf16x8 khi = *(const bf16x8*)&Khi_[(kcol0 + m) * LDSW + g * 8];
      bf16x8 klo = *(const bf16x8*)&Klo_[(kcol0 + m) * LDSW + g * 8];
      f32x4 sc = {0.f, 0.f, 0.f, 0.f};
      sc = __builtin_amdgcn_mfma_f32_16x16x32_bf16(qhi, khi, sc, 0, 0, 0);
      sc = __builtin_amdgcn_mfma_f32_16x16x32_bf16(qhi, klo, sc, 0, 0, 0);
      sc = __builtin_amdgcn_mfma_f32_16x16x32_bf16(qlo, khi, sc, 0, 0, 0);
      const int k_abs = k0 + kcol0 + m;
      const int kcol  = kcol0 + m;
#pragma unroll
      for (int r = 0; r < 4; ++r) {
        float x  = sc[r] * SCALE;
        float a3 = __builtin_fmaf(x, 0.3333333333333333f, 1.0f);
        float a2 = __builtin_fmaf(x * 0.5f, a3, 1.0f);
        float wv = __builtin_fmaf(x, a2, 1.0f);
        wv = (k_abs <= q_lane0 + r) ? wv : 0.0f;
        zacc[r] += wv;
        float wl = wv - trunc_bf(wv);
        unsigned packed = (__float_as_uint(wv) >> 16) |
                          (__float_as_uint(wl) & 0xffff0000u);
        const int q = g * 4 + r;
        Wp[wid][q * 32 + (((kcol >> 2) ^ (q & 7)) << 2) + (kcol & 3)] = packed;
      }
    }

    uint4 pa = *(const uint4*)&Wp[wid][m * 32 + (((2 * g) ^ (m & 7)) << 2)];
    uint4 pb = *(const uint4*)&Wp[wid][m * 32 + (((2 * g + 1) ^ (m & 7)) << 2)];
    union { bf16x8 v; unsigned u[4]; } WH, WL;
    WH.u[0] = (pa.x & 0xffffu) | (pa.y << 16);
    WH.u[1] = (pa.z & 0xffffu) | (pa.w << 16);
    WH.u[2] = (pb.x & 0xffffu) | (pb.y << 16);
    WH.u[3] = (pb.z & 0xffffu) | (pb.w << 16);
    WL.u[0] = (pa.x >> 16) | (pa.y & 0xffff0000u);
    WL.u[1] = (pa.z >> 16) | (pa.w & 0xffff0000u);
    WL.u[2] = (pb.x >> 16) | (pb.y & 0xffff0000u);
    WL.u[3] = (pb.z >> 16) | (pb.w & 0xffff0000u);

#pragma unroll
    for (int ct = 0; ct < 4; ++ct) {
      bf16x8 vhi = *(const bf16x8*)&Vthi_[(ct * 16 + m) * LDSW + g * 8];
      bf16x8 vlo = *(const bf16x8*)&Vtlo_[(ct * 16 + m) * LDSW + g * 8];
      acc[ct] = __builtin_amdgcn_mfma_f32_16x16x32_bf16(WH.v, vhi, acc[ct], 0, 0, 0);
      acc[ct] = __builtin_amdgcn_mfma_f32_16x16x32_bf16(WH.v, vlo, acc[ct], 0, 0, 0);
      acc[ct] = __builtin_amdgcn_mfma_f32_16x16x32_bf16(WL.v, vhi, acc[ct], 0, 0, 0);
    }
  }

  float invz[4];
#pragma unroll
  for (int r = 0; r < 4; ++r) {
    float z = zacc[r];
    z += __shfl_xor(z, 1); z += __shfl_xor(z, 2);
    z += __shfl_xor(z, 4); z += __shfl_xor(z, 8);
    invz[r] = 1.0f / z;
  }

  float* ob = Outg + ((size_t)bh * T_SEQ + (q0 + wq)) * DV;
#pragma unroll
  for (int ct = 0; ct < 4; ++ct)
#pragma unroll
    for (int r = 0; r < 4; ++r)
      ob[(g * 4 + r) * DV + ct * 16 + m] = acc[ct][r] * invz[r];
}

}  // namespace

extern "C" void kernel_launch(void* const* d_in, const int* in_sizes, int n_in,
                              void* d_out, int out_size, void* d_ws, size_t ws_size,
                              hipStream_t stream) {
  const float* Q = (const float*)d_in[0];
  const float* K = (const float*)d_in[1];
  const float* V = (const float*)d_in[2];
  float* Out = (float*)d_out;

  if (ws_size >= WS_NEED && d_ws != nullptr) {
    u16* khi  = (u16*)((char*)d_ws + KHI_OFF);
    u16* klo  = (u16*)((char*)d_ws + KLO_OFF);
    u16* vthi = (u16*)((char*)d_ws + VTHI_OFF);

    hipLaunchKernelGGL(pack_kv, dim3(4096), dim3(256), 0, stream,
                       K, V, khi, klo, vthi);
    hipLaunchKernelGGL(taylor_attn_v5, dim3(2048), dim3(128), 0, stream,
                       Q, khi, klo, vthi, Out);
  } else {
    hipLaunchKernelGGL(taylor_attn_fb, dim3(1024), dim3(256), 0, stream,
                       Q, K, V, Out);
  }
}

// Round 6
// 63.080 us; speedup vs baseline: 5.6197x; 1.0811x over previous
//
#include <hip/hip_runtime.h>
#include <hip/hip_bf16.h>

// Taylor attention v6: strip-PAIRED blocks (uniform 65 steps/block regardless
// of dispatch mapping), 4 waves per block with stride-4 key interleave and a
// 4-slice LDS combine. Per-step math identical to v5: swapped-QK^T 32x32x16
// split-bf16 scores, RNE-bf16 W/V PV, permlane32_swap W transpose.

typedef __attribute__((ext_vector_type(8))) short bf16x8;
typedef __attribute__((ext_vector_type(4))) float f32x4;
typedef __attribute__((ext_vector_type(16))) float f32x16;
typedef unsigned int u32;
typedef unsigned short u16;

namespace {

constexpr int T_SEQ = 2048;
constexpr int DK    = 32;
constexpr int DV    = 64;
constexpr int NBH   = 32;

// w = ((C3*s + C2)*s + C1)*s + 1  with s = raw dot (1/sqrt(32) folded in)
constexpr float C1 = 0.17677669529663687f;   // c
constexpr float C2 = 0.015625f;              // c^2/2 (exact)
constexpr float C3 = 9.2071195e-4f;          // c^3/6

// workspace layout (bytes): Khi 4MiB | Klo 4MiB | Vthi 8MiB
constexpr size_t KHI_OFF  = 0;
constexpr size_t KLO_OFF  = (size_t)NBH * T_SEQ * DK * 2;             //  4 MiB
constexpr size_t VTHI_OFF = KLO_OFF * 2;                              //  8 MiB
constexpr size_t WS_NEED  = VTHI_OFF + (size_t)NBH * DV * T_SEQ * 2;  // 16 MiB

__device__ __forceinline__ u32 pack_hi2(float f0, float f1) {
  return (__float_as_uint(f0) >> 16) | (__float_as_uint(f1) & 0xffff0000u);
}
__device__ __forceinline__ float trunc_bf(float f) {
  return __uint_as_float(__float_as_uint(f) & 0xffff0000u);
}
__device__ __forceinline__ u16 bfhi(float f) { return (u16)(__float_as_uint(f) >> 16); }

// RNE bf16 pair pack (compiler lowers to v_cvt_pk_bf16_f32)
__device__ __forceinline__ u32 pack_rn2(float f0, float f1) {
  union { __hip_bfloat16 h; u16 u; } a, b;
  a.h = __hip_bfloat16(f0);
  b.h = __hip_bfloat16(f1);
  return (u32)a.u | ((u32)b.u << 16);
}

// Swap a.lanes[32:63] <-> b.lanes[0:31].
__device__ __forceinline__ void permswap(u32& a, u32& b) {
  asm volatile("v_permlane32_swap_b32 %0, %1" : "+v"(a), "+v"(b));
}

// ---------------- pack kernel (K split-bf16; V^T RNE-bf16) ----------------

__global__ void pack_kv(const float* __restrict__ Kg, const float* __restrict__ Vg,
                        u16* __restrict__ Khi, u16* __restrict__ Klo,
                        u16* __restrict__ Vthi) {
  __shared__ float tile[DV][33];
  const int bid = blockIdx.x;
  const int t   = threadIdx.x;
  if (bid < 2048) {  // ---- K: elementwise split (truncation hi + residual lo)
    size_t i = ((size_t)bid * 256 + t) * 4;
    float4 f = *(const float4*)(Kg + i);
    ushort4 h, l;
    h.x = bfhi(f.x); h.y = bfhi(f.y); h.z = bfhi(f.z); h.w = bfhi(f.w);
    l.x = bfhi(f.x - trunc_bf(f.x)); l.y = bfhi(f.y - trunc_bf(f.y));
    l.z = bfhi(f.z - trunc_bf(f.z)); l.w = bfhi(f.w - trunc_bf(f.w));
    *(ushort4*)(Khi + i) = h;
    *(ushort4*)(Klo + i) = l;
  } else {           // ---- V: transpose 32k x 64c tiles, RNE hi only
    const int vb = bid - 2048;
    const int bh = vb >> 6;
    const int k0 = (vb & 63) * 32;
    {
      const int kl = t >> 3, c0 = (t & 7) * 8;
      const float* src = Vg + ((size_t)bh * T_SEQ + k0 + kl) * DV + c0;
      float4 a = *(const float4*)src;
      float4 b = *(const float4*)(src + 4);
      tile[c0 + 0][kl] = a.x; tile[c0 + 1][kl] = a.y;
      tile[c0 + 2][kl] = a.z; tile[c0 + 3][kl] = a.w;
      tile[c0 + 4][kl] = b.x; tile[c0 + 5][kl] = b.y;
      tile[c0 + 6][kl] = b.z; tile[c0 + 7][kl] = b.w;
    }
    __syncthreads();
    {
      const int cl = t >> 2, k8 = (t & 3) * 8;
      u32 h[4];
#pragma unroll
      for (int j = 0; j < 4; ++j)
        h[j] = pack_rn2(tile[cl][k8 + 2 * j], tile[cl][k8 + 2 * j + 1]);
      size_t off = ((size_t)(bh * DV + cl)) * T_SEQ + k0 + k8;
      *(uint4*)(Vthi + off) = make_uint4(h[0], h[1], h[2], h[3]);
    }
  }
}

// ---------------- main kernel (v6) ----------------

__global__ __launch_bounds__(256, 4)
void taylor_attn_v6(const float* __restrict__ Qg, const u16* __restrict__ Khi,
                    const u16* __restrict__ Klo, const u16* __restrict__ Vthi,
                    float* __restrict__ Outg) {
  __shared__ __align__(16) float Sp[4 * 2048];  // 4 wave partials, 32 KB
  __shared__ float Zp[4 * 32];

  const int tid = threadIdx.x;
  const int l   = tid & 63;
  const int w   = tid >> 6;
  const int cq  = l & 31;
  const int hi  = l >> 5;

  // decode: 8 XCDs x 4 bh x 32 strip-pairs. Every block = exactly 65 steps
  // (strip p then strip 63-p) -> uniform work under ANY dispatch mapping.
  const int bid = blockIdx.x;
  const int xcd = bid & 7;
  const int r_  = bid >> 3;            // 0..127
  const int bh  = xcd * 4 + (r_ & 3);
  const int p   = r_ >> 2;             // 0..31

  const u16* kbh_hi = Khi + (size_t)bh * T_SEQ * DK;
  const u16* kbh_lo = Klo + (size_t)bh * T_SEQ * DK;
  const u16* vbh_hi = Vthi + (size_t)bh * DV * T_SEQ;
  const float* qb   = Qg + (size_t)bh * T_SEQ * DK;

#pragma unroll 1
  for (int ph = 0; ph < 2; ++ph) {
    const int s  = ph ? (63 - p) : p;
    const int q0 = s * 32;

    if (ph) __syncthreads();  // phase-A combine reads done before Sp reuse

    // ---- Q B-fragments (full split: trunc hi + residual lo)
    bf16x8 qfh[2], qfl[2];
#pragma unroll
    for (int t = 0; t < 2; ++t) {
      const float* qp = qb + (size_t)(q0 + cq) * DK + t * 16 + hi * 8;
      float4 a = *(const float4*)qp;
      float4 b = *(const float4*)(qp + 4);
      union { bf16x8 v; u32 u[4]; } H, L;
      H.u[0] = pack_hi2(a.x, a.y); H.u[1] = pack_hi2(a.z, a.w);
      H.u[2] = pack_hi2(b.x, b.y); H.u[3] = pack_hi2(b.z, b.w);
      L.u[0] = pack_hi2(a.x - trunc_bf(a.x), a.y - trunc_bf(a.y));
      L.u[1] = pack_hi2(a.z - trunc_bf(a.z), a.w - trunc_bf(a.w));
      L.u[2] = pack_hi2(b.x - trunc_bf(b.x), b.y - trunc_bf(b.y));
      L.u[3] = pack_hi2(b.z - trunc_bf(b.z), b.w - trunc_bf(b.w));
      qfh[t] = H.v; qfl[t] = L.v;
    }

    f32x16 acc[2];
#pragma unroll
    for (int ct = 0; ct < 2; ++ct)
#pragma unroll
      for (int r = 0; r < 16; ++r) acc[ct][r] = 0.f;
    float zacc = 0.f;

    // ---- stride-4 key interleave: wave w owns kt = w, w+4, ... (<= s)
    for (int kt = w; kt <= s; kt += 4) {
      const int k0 = kt * 32;

      // K A-fragments (L2-hot)
      bf16x8 kfh[2], kfl[2];
#pragma unroll
      for (int t = 0; t < 2; ++t) {
        size_t off = (size_t)(k0 + cq) * DK + t * 16 + hi * 8;
        kfh[t] = *(const bf16x8*)(kbh_hi + off);
        kfl[t] = *(const bf16x8*)(kbh_lo + off);
      }
      // V B-fragments issued early (consumed at end of body)
      bf16x8 vfr[4];
#pragma unroll
      for (int ct = 0; ct < 2; ++ct)
#pragma unroll
        for (int t = 0; t < 2; ++t)
          vfr[ct * 2 + t] = *(const bf16x8*)(
              vbh_hi + (size_t)(ct * 32 + cq) * T_SEQ + k0 + t * 16 + hi * 8);

      // swapped scores, two parallel 3-chains then merge
      f32x16 d0, d1;
#pragma unroll
      for (int r = 0; r < 16; ++r) { d0[r] = 0.f; d1[r] = 0.f; }
      d0 = __builtin_amdgcn_mfma_f32_32x32x16_bf16(kfh[0], qfh[0], d0, 0, 0, 0);
      d1 = __builtin_amdgcn_mfma_f32_32x32x16_bf16(kfh[1], qfh[1], d1, 0, 0, 0);
      d0 = __builtin_amdgcn_mfma_f32_32x32x16_bf16(kfh[0], qfl[0], d0, 0, 0, 0);
      d1 = __builtin_amdgcn_mfma_f32_32x32x16_bf16(kfh[1], qfl[1], d1, 0, 0, 0);
      d0 = __builtin_amdgcn_mfma_f32_32x32x16_bf16(kfl[0], qfh[0], d0, 0, 0, 0);
      d1 = __builtin_amdgcn_mfma_f32_32x32x16_bf16(kfl[1], qfh[1], d1, 0, 0, 0);

      // poly + (diagonal) mask + Z
      float wv[16];
      const bool diag = (kt == s);
#pragma unroll
      for (int r = 0; r < 16; ++r) {
        float sc = d0[r] + d1[r];
        float t_ = __builtin_fmaf(sc, C3, C2);
        t_       = __builtin_fmaf(sc, t_, C1);
        float wr = __builtin_fmaf(sc, t_, 1.0f);
        if (diag) {
          const int krel = (r & 3) + 8 * (r >> 2) + 4 * hi;
          wr = (krel <= cq) ? wr : 0.f;
        }
        zacc += wr;
        wv[r] = wr;
      }

      // W -> RNE bf16, in-register transpose to PV A-frags
      union { bf16x8 v; u32 u[4]; } WH[2];
#pragma unroll
      for (int t = 0; t < 2; ++t) {
        const int b = t * 8;
        u32 p0 = pack_rn2(wv[b + 0], wv[b + 1]);
        u32 p1 = pack_rn2(wv[b + 2], wv[b + 3]);
        u32 p2 = pack_rn2(wv[b + 4], wv[b + 5]);
        u32 p3 = pack_rn2(wv[b + 6], wv[b + 7]);
        permswap(p0, p2); permswap(p1, p3);
        WH[t].u[0] = p0; WH[t].u[1] = p1; WH[t].u[2] = p2; WH[t].u[3] = p3;
      }

      // PV: 4 MFMAs
#pragma unroll
      for (int ct = 0; ct < 2; ++ct)
#pragma unroll
        for (int t = 0; t < 2; ++t)
          acc[ct] = __builtin_amdgcn_mfma_f32_32x32x16_bf16(WH[t].v, vfr[ct * 2 + t],
                                                            acc[ct], 0, 0, 0);
    }

    // ---- publish Z + S partials (all 4 waves)
    {
      float zt = zacc + __shfl_xor(zacc, 32);
      if (hi == 0) Zp[w * 32 + cq] = zt;
    }
#pragma unroll
    for (int ct = 0; ct < 2; ++ct)
#pragma unroll
      for (int r = 0; r < 16; ++r) {
        const int qr = (r & 3) + 8 * (r >> 2) + 4 * hi;
        Sp[w * 2048 + qr * 64 + ct * 32 + cq] = acc[ct][r];
      }
    __syncthreads();

    // ---- combine 4 slices + divide + store (2 float4 per thread)
    const f32x4* S4 = (const f32x4*)Sp;
#pragma unroll
    for (int i = 0; i < 2; ++i) {
      const int e4  = tid + i * 256;     // 0..511 float4s of the 32x64 tile
      const int row = e4 >> 4;
      f32x4 ssum = S4[e4] + S4[512 + e4] + S4[1024 + e4] + S4[1536 + e4];
      float z = Zp[row] + Zp[32 + row] + Zp[64 + row] + Zp[96 + row];
      float inv = 1.0f / z;
      float4 o;
      o.x = ssum[0] * inv; o.y = ssum[1] * inv;
      o.z = ssum[2] * inv; o.w = ssum[3] * inv;
      *(float4*)(Outg + ((size_t)bh * T_SEQ + q0 + row) * DV + (e4 & 15) * 4) = o;
    }
  }
}

// ---------------- fallback (no workspace): v2 staged-LDS kernel ----------------

constexpr int QT_FB = 64;
constexpr int KT_FB = 32;
constexpr int LDSW  = 40;
constexpr float SCALE = 0.17677669529663687f;

__global__ __launch_bounds__(256, 4)
void taylor_attn_fb(const float* __restrict__ Qg, const float* __restrict__ Kg,
                    const float* __restrict__ Vg, float* __restrict__ Outg) {
  __shared__ __align__(16) unsigned short Qhi[QT_FB * LDSW], Qlo[QT_FB * LDSW];
  __shared__ __align__(16) unsigned short Khi_[KT_FB * LDSW], Klo_[KT_FB * LDSW];
  __shared__ __align__(16) unsigned short Vthi_[DV * LDSW], Vtlo_[DV * LDSW];
  __shared__ __align__(16) unsigned Wp[4][16 * 32];

  const int tid  = threadIdx.x;
  const int lane = tid & 63;
  const int wid  = tid >> 6;
  const int m    = lane & 15;
  const int g    = lane >> 4;

  const int bid = blockIdx.x;
  const int v   = bid >> 3;
  const int bh  = (bid & 7) * 4 + (v >> 5);
  const int qt  = 31 - (v & 31);
  const int q0  = qt * QT_FB;

  const float* Qbase = Qg + ((size_t)bh * T_SEQ + q0) * DK;
  const float* Kbase = Kg + (size_t)bh * T_SEQ * DK;
  const float* Vbase = Vg + (size_t)bh * T_SEQ * DV;

#pragma unroll
  for (int p = 0; p < 2; ++p) {
    int e = tid + p * 256, row = e >> 3, c4 = (e & 7) * 4;
    float4 f = *(const float4*)(Qbase + row * DK + c4);
    uint2 h, l;
    h.x = pack_hi2(f.x, f.y); h.y = pack_hi2(f.z, f.w);
    l.x = pack_hi2(f.x - trunc_bf(f.x), f.y - trunc_bf(f.y));
    l.y = pack_hi2(f.z - trunc_bf(f.z), f.w - trunc_bf(f.w));
    *(uint2*)&Qhi[row * LDSW + c4] = h;
    *(uint2*)&Qlo[row * LDSW + c4] = l;
  }
  __syncthreads();

  const int wq = wid * 16;
  const bf16x8 qhi = *(const bf16x8*)&Qhi[(wq + m) * LDSW + g * 8];
  const bf16x8 qlo = *(const bf16x8*)&Qlo[(wq + m) * LDSW + g * 8];

  f32x4 acc[4];
#pragma unroll
  for (int ct = 0; ct < 4; ++ct) acc[ct] = f32x4{0.f, 0.f, 0.f, 0.f};
  float zacc[4] = {0.f, 0.f, 0.f, 0.f};

  const int q_lane0 = q0 + wq + g * 4;
  const int q_wave_max = q0 + wq + 15;

  const int nkt = (q0 + QT_FB) / KT_FB;
  for (int kt = 0; kt < nkt; ++kt) {
    const int k0 = kt * KT_FB;
    __syncthreads();
    {
      int row = tid >> 3, c4 = (tid & 7) * 4;
      float4 f = *(const float4*)(Kbase + (size_t)(k0 + row) * DK + c4);
      uint2 h, l;
      h.x = pack_hi2(f.x, f.y); h.y = pack_hi2(f.z, f.w);
      l.x = pack_hi2(f.x - trunc_bf(f.x), f.y - trunc_bf(f.y));
      l.y = pack_hi2(f.z - trunc_bf(f.z), f.w - trunc_bf(f.w));
      *(uint2*)&Khi_[row * LDSW + c4] = h;
      *(uint2*)&Klo_[row * LDSW + c4] = l;
    }
    {
      int kk = (tid & 15) * 2, c4 = (tid >> 4) * 4;
      const float* vp = Vbase + (size_t)(k0 + kk) * DV + c4;
      float4 a = *(const float4*)vp;
      float4 b = *(const float4*)(vp + DV);
      float af[4] = {a.x, a.y, a.z, a.w};
      float bf_[4] = {b.x, b.y, b.z, b.w};
#pragma unroll
      for (int jj = 0; jj < 4; ++jj) {
        *(unsigned*)&Vthi_[(c4 + jj) * LDSW + kk] = pack_hi2(af[jj], bf_[jj]);
        *(unsigned*)&Vtlo_[(c4 + jj) * LDSW + kk] =
            pack_hi2(af[jj] - trunc_bf(af[jj]), bf_[jj] - trunc_bf(bf_[jj]));
      }
    }
    __syncthreads();

    if (k0 > q_wave_max) continue;

#pragma unroll
    for (int k16 = 0; k16 < 2; ++k16) {
      const int kcol0 = k16 * 16;
      bf16x8 khi = *(const bf16x8*)&Khi_[(kcol0 + m) * LDSW + g * 8];
      bf16x8 klo = *(const bf16x8*)&Klo_[(kcol0 + m) * LDSW + g * 8];
      f32x4 sc = {0.f, 0.f, 0.f, 0.f};
      sc = __builtin_amdgcn_mfma_f32_16x16x32_bf16(qhi, khi, sc, 0, 0, 0);
      sc = __builtin_amdgcn_mfma_f32_16x16x32_bf16(qhi, klo, sc, 0, 0, 0);
      sc = __builtin_amdgcn_mfma_f32_16x16x32_bf16(qlo, khi, sc, 0, 0, 0);
      const int k_abs = k0 + kcol0 + m;
      const int kcol  = kcol0 + m;
#pragma unroll
      for (int r = 0; r < 4; ++r) {
        float x  = sc[r] * SCALE;
        float a3 = __builtin_fmaf(x, 0.3333333333333333f, 1.0f);
        float a2 = __builtin_fmaf(x * 0.5f, a3, 1.0f);
        float wvv = __builtin_fmaf(x, a2, 1.0f);
        wvv = (k_abs <= q_lane0 + r) ? wvv : 0.0f;
        zacc[r] += wvv;
        float wl = wvv - trunc_bf(wvv);
        unsigned packed = (__float_as_uint(wvv) >> 16) |
                          (__float_as_uint(wl) & 0xffff0000u);
        const int q = g * 4 + r;
        Wp[wid][q * 32 + (((kcol >> 2) ^ (q & 7)) << 2) + (kcol & 3)] = packed;
      }
    }

    uint4 pa = *(const uint4*)&Wp[wid][m * 32 + (((2 * g) ^ (m & 7)) << 2)];
    uint4 pb = *(const uint4*)&Wp[wid][m * 32 + (((2 * g + 1) ^ (m & 7)) << 2)];
    union { bf16x8 v; unsigned u[4]; } WH, WL;
    WH.u[0] = (pa.x & 0xffffu) | (pa.y << 16);
    WH.u[1] = (pa.z & 0xffffu) | (pa.w << 16);
    WH.u[2] = (pb.x & 0xffffu) | (pb.y << 16);
    WH.u[3] = (pb.z & 0xffffu) | (pb.w << 16);
    WL.u[0] = (pa.x >> 16) | (pa.y & 0xffff0000u);
    WL.u[1] = (pa.z >> 16) | (pa.w & 0xffff0000u);
    WL.u[2] = (pb.x >> 16) | (pb.y & 0xffff0000u);
    WL.u[3] = (pb.z >> 16) | (pb.w & 0xffff0000u);

#pragma unroll
    for (int ct = 0; ct < 4; ++ct) {
      bf16x8 vhi = *(const bf16x8*)&Vthi_[(ct * 16 + m) * LDSW + g * 8];
      bf16x8 vlo = *(const bf16x8*)&Vtlo_[(ct * 16 + m) * LDSW + g * 8];
      acc[ct] = __builtin_amdgcn_mfma_f32_16x16x32_bf16(WH.v, vhi, acc[ct], 0, 0, 0);
      acc[ct] = __builtin_amdgcn_mfma_f32_16x16x32_bf16(WH.v, vlo, acc[ct], 0, 0, 0);
      acc[ct] = __builtin_amdgcn_mfma_f32_16x16x32_bf16(WL.v, vhi, acc[ct], 0, 0, 0);
    }
  }

  float invz[4];
#pragma unroll
  for (int r = 0; r < 4; ++r) {
    float z = zacc[r];
    z += __shfl_xor(z, 1); z += __shfl_xor(z, 2);
    z += __shfl_xor(z, 4); z += __shfl_xor(z, 8);
    invz[r] = 1.0f / z;
  }

  float* ob = Outg + ((size_t)bh * T_SEQ + (q0 + wq)) * DV;
#pragma unroll
  for (int ct = 0; ct < 4; ++ct)
#pragma unroll
    for (int r = 0; r < 4; ++r)
      ob[(g * 4 + r) * DV + ct * 16 + m] = acc[ct][r] * invz[r];
}

}  // namespace

extern "C" void kernel_launch(void* const* d_in, const int* in_sizes, int n_in,
                              void* d_out, int out_size, void* d_ws, size_t ws_size,
                              hipStream_t stream) {
  const float* Q = (const float*)d_in[0];
  const float* K = (const float*)d_in[1];
  const float* V = (const float*)d_in[2];
  float* Out = (float*)d_out;

  if (ws_size >= WS_NEED && d_ws != nullptr) {
    u16* khi  = (u16*)((char*)d_ws + KHI_OFF);
    u16* klo  = (u16*)((char*)d_ws + KLO_OFF);
    u16* vthi = (u16*)((char*)d_ws + VTHI_OFF);

    hipLaunchKernelGGL(pack_kv, dim3(4096), dim3(256), 0, stream,
                       K, V, khi, klo, vthi);
    hipLaunchKernelGGL(taylor_attn_v6, dim3(1024), dim3(256), 0, stream,
                       Q, khi, klo, vthi, Out);
  } else {
    hipLaunchKernelGGL(taylor_attn_fb, dim3(1024), dim3(256), 0, stream,
                       Q, K, V, Out);
  }
}

// Round 7
// 55.694 us; speedup vs baseline: 6.3650x; 1.1326x over previous
//
#include <hip/hip_runtime.h>
#include <hip/hip_bf16.h>

// Taylor attention v7: fp16 single-MFMA QK^T (error budget allows it; PV stays
// RNE-bf16), register-double-buffered K prefetch + early-issued V (latency
// hiding), diagonal step peeled out of the hot loop. Schedule as v6:
// strip-paired uniform 65-step blocks, 4 waves stride-4 key interleave,
// 4-slice LDS combine.

typedef __attribute__((ext_vector_type(8))) short bf16x8;
typedef __attribute__((ext_vector_type(8))) _Float16 f16x8;
typedef __attribute__((ext_vector_type(4))) float f32x4;
typedef __attribute__((ext_vector_type(16))) float f32x16;
typedef unsigned int u32;
typedef unsigned short u16;

namespace {

constexpr int T_SEQ = 2048;
constexpr int DK    = 32;
constexpr int DV    = 64;
constexpr int NBH   = 32;

// w = ((C3*s + C2)*s + C1)*s + 1  with s = raw dot (1/sqrt(32) folded in)
constexpr float C1 = 0.17677669529663687f;   // c
constexpr float C2 = 0.015625f;              // c^2/2 (exact)
constexpr float C3 = 9.2071195e-4f;          // c^3/6

// workspace layout (bytes): Khf (fp16) 4MiB | Vthi (bf16) 8MiB
constexpr size_t KHF_OFF  = 0;
constexpr size_t VTHI_OFF = (size_t)NBH * T_SEQ * DK * 2;             //  4 MiB
constexpr size_t WS_NEED  = VTHI_OFF + (size_t)NBH * DV * T_SEQ * 2;  // 12 MiB

__device__ __forceinline__ u32 pack_hi2(float f0, float f1) {
  return (__float_as_uint(f0) >> 16) | (__float_as_uint(f1) & 0xffff0000u);
}
__device__ __forceinline__ float trunc_bf(float f) {
  return __uint_as_float(__float_as_uint(f) & 0xffff0000u);
}
__device__ __forceinline__ u16 f2h(float f) {
  union { _Float16 h; u16 u; } c;
  c.h = (_Float16)f;             // RNE
  return c.u;
}
// RNE bf16 pair pack (compiler lowers to v_cvt_pk_bf16_f32)
__device__ __forceinline__ u32 pack_rn2(float f0, float f1) {
  union { __hip_bfloat16 h; u16 u; } a, b;
  a.h = __hip_bfloat16(f0);
  b.h = __hip_bfloat16(f1);
  return (u32)a.u | ((u32)b.u << 16);
}
// Swap a.lanes[32:63] <-> b.lanes[0:31].
__device__ __forceinline__ void permswap(u32& a, u32& b) {
  asm volatile("v_permlane32_swap_b32 %0, %1" : "+v"(a), "+v"(b));
}

// ---------------- pack kernel (K -> fp16; V^T -> RNE bf16) ----------------

__global__ void pack_kv(const float* __restrict__ Kg, const float* __restrict__ Vg,
                        u16* __restrict__ Khf, u16* __restrict__ Vthi) {
  __shared__ float tile[DV][33];
  const int bid = blockIdx.x;
  const int t   = threadIdx.x;
  if (bid < 2048) {  // ---- K: elementwise fp16 convert
    size_t i = ((size_t)bid * 256 + t) * 4;
    float4 f = *(const float4*)(Kg + i);
    ushort4 h;
    h.x = f2h(f.x); h.y = f2h(f.y); h.z = f2h(f.z); h.w = f2h(f.w);
    *(ushort4*)(Khf + i) = h;
  } else {           // ---- V: transpose 32k x 64c tiles, RNE bf16
    const int vb = bid - 2048;
    const int bh = vb >> 6;
    const int k0 = (vb & 63) * 32;
    {
      const int kl = t >> 3, c0 = (t & 7) * 8;
      const float* src = Vg + ((size_t)bh * T_SEQ + k0 + kl) * DV + c0;
      float4 a = *(const float4*)src;
      float4 b = *(const float4*)(src + 4);
      tile[c0 + 0][kl] = a.x; tile[c0 + 1][kl] = a.y;
      tile[c0 + 2][kl] = a.z; tile[c0 + 3][kl] = a.w;
      tile[c0 + 4][kl] = b.x; tile[c0 + 5][kl] = b.y;
      tile[c0 + 6][kl] = b.z; tile[c0 + 7][kl] = b.w;
    }
    __syncthreads();
    {
      const int cl = t >> 2, k8 = (t & 3) * 8;
      u32 h[4];
#pragma unroll
      for (int j = 0; j < 4; ++j)
        h[j] = pack_rn2(tile[cl][k8 + 2 * j], tile[cl][k8 + 2 * j + 1]);
      size_t off = ((size_t)(bh * DV + cl)) * T_SEQ + k0 + k8;
      *(uint4*)(Vthi + off) = make_uint4(h[0], h[1], h[2], h[3]);
    }
  }
}

// ---------------- main kernel (v7) ----------------

__global__ __launch_bounds__(256, 4)
void taylor_attn_v7(const float* __restrict__ Qg, const u16* __restrict__ Khf,
                    const u16* __restrict__ Vthi, float* __restrict__ Outg) {
  __shared__ __align__(16) float Sp[4 * 2048];  // 4 wave partials, 32 KB
  __shared__ float Zp[4 * 32];

  const int tid = threadIdx.x;
  const int l   = tid & 63;
  const int w   = tid >> 6;
  const int cq  = l & 31;
  const int hi  = l >> 5;

  // decode: 8 XCDs x 4 bh x 32 strip-pairs; every block = exactly 65 steps.
  const int bid = blockIdx.x;
  const int xcd = bid & 7;
  const int r_  = bid >> 3;
  const int bh  = xcd * 4 + (r_ & 3);
  const int p   = r_ >> 2;

  // strength-reduced per-lane base pointers
  const u16* kq = Khf + (size_t)bh * T_SEQ * DK + (size_t)cq * DK + hi * 8;
  const u16* vq = Vthi + (size_t)bh * DV * T_SEQ + (size_t)cq * T_SEQ + hi * 8;
  const float* qb = Qg + (size_t)bh * T_SEQ * DK;

#pragma unroll 1
  for (int ph = 0; ph < 2; ++ph) {
    const int s  = ph ? (63 - p) : p;
    const int q0 = s * 32;

    if (ph) __syncthreads();  // combine reads of Sp done before reuse

    // ---- Q B-fragments, fp16 RNE
    f16x8 qf[2];
#pragma unroll
    for (int t = 0; t < 2; ++t) {
      const float* qp = qb + (size_t)(q0 + cq) * DK + t * 16 + hi * 8;
      float4 a = *(const float4*)qp;
      float4 b = *(const float4*)(qp + 4);
      f16x8 v;
      v[0] = (_Float16)a.x; v[1] = (_Float16)a.y;
      v[2] = (_Float16)a.z; v[3] = (_Float16)a.w;
      v[4] = (_Float16)b.x; v[5] = (_Float16)b.y;
      v[6] = (_Float16)b.z; v[7] = (_Float16)b.w;
      qf[t] = v;
    }

    f32x16 acc0, acc1;
#pragma unroll
    for (int r = 0; r < 16; ++r) { acc0[r] = 0.f; acc1[r] = 0.f; }
    float zacc = 0.f;

    auto LOADK = [&](f16x8* kf, int kt) {
      const u16* kp = kq + (size_t)kt * 1024;     // kt*32 rows * DK
      kf[0] = *(const f16x8*)kp;
      kf[1] = *(const f16x8*)(kp + 16);
    };
    auto LOADV = [&](bf16x8* vf, int kt) {
#pragma unroll
      for (int ct = 0; ct < 2; ++ct)
#pragma unroll
        for (int t = 0; t < 2; ++t)
          vf[ct * 2 + t] = *(const bf16x8*)(
              vq + (size_t)ct * 32 * T_SEQ + kt * 32 + t * 16);
    };
    auto STEP = [&](const f16x8* kf, const bf16x8* vf, bool diag) {
      f32x16 d;
#pragma unroll
      for (int r = 0; r < 16; ++r) d[r] = 0.f;
      d = __builtin_amdgcn_mfma_f32_32x32x16_f16(kf[0], qf[0], d, 0, 0, 0);
      d = __builtin_amdgcn_mfma_f32_32x32x16_f16(kf[1], qf[1], d, 0, 0, 0);
      float wv[16];
#pragma unroll
      for (int r = 0; r < 16; ++r) {
        float sc = d[r];
        float t_ = __builtin_fmaf(sc, C3, C2);
        t_       = __builtin_fmaf(sc, t_, C1);
        float wr = __builtin_fmaf(sc, t_, 1.0f);
        if (diag) {
          const int krel = (r & 3) + 8 * (r >> 2) + 4 * hi;
          wr = (krel <= cq) ? wr : 0.f;
        }
        zacc += wr;
        wv[r] = wr;
      }
      union { bf16x8 v; u32 u[4]; } WH[2];
#pragma unroll
      for (int t = 0; t < 2; ++t) {
        const int b = t * 8;
        u32 p0 = pack_rn2(wv[b + 0], wv[b + 1]);
        u32 p1 = pack_rn2(wv[b + 2], wv[b + 3]);
        u32 p2 = pack_rn2(wv[b + 4], wv[b + 5]);
        u32 p3 = pack_rn2(wv[b + 6], wv[b + 7]);
        permswap(p0, p2); permswap(p1, p3);
        WH[t].u[0] = p0; WH[t].u[1] = p1; WH[t].u[2] = p2; WH[t].u[3] = p3;
      }
      acc0 = __builtin_amdgcn_mfma_f32_32x32x16_bf16(WH[0].v, vf[0], acc0, 0, 0, 0);
      acc0 = __builtin_amdgcn_mfma_f32_32x32x16_bf16(WH[1].v, vf[1], acc0, 0, 0, 0);
      acc1 = __builtin_amdgcn_mfma_f32_32x32x16_bf16(WH[0].v, vf[2], acc1, 0, 0, 0);
      acc1 = __builtin_amdgcn_mfma_f32_32x32x16_bf16(WH[1].v, vf[3], acc1, 0, 0, 0);
    };

    // ---- pipelined main loop: kt < s (mask-free), K reg-double-buffered
    int kt = w;
    f16x8 kA[2], kB[2];
    if (kt < s) {
      LOADK(kA, kt);
      while (true) {
        int kn = kt + 4;
        if (kn < s) {
          LOADK(kB, kn);                 // prefetch next K
          bf16x8 vf[4]; LOADV(vf, kt);   // V issued early, used after poly
          STEP(kA, vf, false);
          kt = kn;
        } else {
          bf16x8 vf[4]; LOADV(vf, kt);
          STEP(kA, vf, false);
          break;
        }
        kn = kt + 4;
        if (kn < s) {
          LOADK(kA, kn);
          bf16x8 vf[4]; LOADV(vf, kt);
          STEP(kB, vf, false);
          kt = kn;
        } else {
          bf16x8 vf[4]; LOADV(vf, kt);
          STEP(kB, vf, false);
          break;
        }
      }
    }
    // ---- peeled diagonal step (owner wave only, masked)
    if ((s & 3) == w) {
      f16x8 kD[2]; LOADK(kD, s);
      bf16x8 vf[4]; LOADV(vf, s);
      STEP(kD, vf, true);
    }

    // ---- publish Z + S partials
    {
      float zt = zacc + __shfl_xor(zacc, 32);
      if (hi == 0) Zp[w * 32 + cq] = zt;
    }
#pragma unroll
    for (int r = 0; r < 16; ++r) {
      const int qr = (r & 3) + 8 * (r >> 2) + 4 * hi;
      Sp[w * 2048 + qr * 64 + cq]      = acc0[r];
      Sp[w * 2048 + qr * 64 + 32 + cq] = acc1[r];
    }
    __syncthreads();

    // ---- combine 4 slices + divide + store
    const f32x4* S4 = (const f32x4*)Sp;
#pragma unroll
    for (int i = 0; i < 2; ++i) {
      const int e4  = tid + i * 256;
      const int row = e4 >> 4;
      f32x4 ssum = S4[e4] + S4[512 + e4] + S4[1024 + e4] + S4[1536 + e4];
      float z = Zp[row] + Zp[32 + row] + Zp[64 + row] + Zp[96 + row];
      float inv = 1.0f / z;
      float4 o;
      o.x = ssum[0] * inv; o.y = ssum[1] * inv;
      o.z = ssum[2] * inv; o.w = ssum[3] * inv;
      *(float4*)(Outg + ((size_t)bh * T_SEQ + q0 + row) * DV + (e4 & 15) * 4) = o;
    }
  }
}

// ---------------- fallback (no workspace): v2 staged-LDS kernel ----------------

constexpr int QT_FB = 64;
constexpr int KT_FB = 32;
constexpr int LDSW  = 40;
constexpr float SCALE = 0.17677669529663687f;

__global__ __launch_bounds__(256, 4)
void taylor_attn_fb(const float* __restrict__ Qg, const float* __restrict__ Kg,
                    const float* __restrict__ Vg, float* __restrict__ Outg) {
  __shared__ __align__(16) unsigned short Qhi[QT_FB * LDSW], Qlo[QT_FB * LDSW];
  __shared__ __align__(16) unsigned short Khi_[KT_FB * LDSW], Klo_[KT_FB * LDSW];
  __shared__ __align__(16) unsigned short Vthi_[DV * LDSW], Vtlo_[DV * LDSW];
  __shared__ __align__(16) unsigned Wp[4][16 * 32];

  const int tid  = threadIdx.x;
  const int lane = tid & 63;
  const int wid  = tid >> 6;
  const int m    = lane & 15;
  const int g    = lane >> 4;

  const int bid = blockIdx.x;
  const int v   = bid >> 3;
  const int bh  = (bid & 7) * 4 + (v >> 5);
  const int qt  = 31 - (v & 31);
  const int q0  = qt * QT_FB;

  const float* Qbase = Qg + ((size_t)bh * T_SEQ + q0) * DK;
  const float* Kbase = Kg + (size_t)bh * T_SEQ * DK;
  const float* Vbase = Vg + (size_t)bh * T_SEQ * DV;

#pragma unroll
  for (int p = 0; p < 2; ++p) {
    int e = tid + p * 256, row = e >> 3, c4 = (e & 7) * 4;
    float4 f = *(const float4*)(Qbase + row * DK + c4);
    uint2 h, l;
    h.x = pack_hi2(f.x, f.y); h.y = pack_hi2(f.z, f.w);
    l.x = pack_hi2(f.x - trunc_bf(f.x), f.y - trunc_bf(f.y));
    l.y = pack_hi2(f.z - trunc_bf(f.z), f.w - trunc_bf(f.w));
    *(uint2*)&Qhi[row * LDSW + c4] = h;
    *(uint2*)&Qlo[row * LDSW + c4] = l;
  }
  __syncthreads();

  const int wq = wid * 16;
  const bf16x8 qhi = *(const bf16x8*)&Qhi[(wq + m) * LDSW + g * 8];
  const bf16x8 qlo = *(const bf16x8*)&Qlo[(wq + m) * LDSW + g * 8];

  f32x4 acc[4];
#pragma unroll
  for (int ct = 0; ct < 4; ++ct) acc[ct] = f32x4{0.f, 0.f, 0.f, 0.f};
  float zacc[4] = {0.f, 0.f, 0.f, 0.f};

  const int q_lane0 = q0 + wq + g * 4;
  const int q_wave_max = q0 + wq + 15;

  const int nkt = (q0 + QT_FB) / KT_FB;
  for (int kt = 0; kt < nkt; ++kt) {
    const int k0 = kt * KT_FB;
    __syncthreads();
    {
      int row = tid >> 3, c4 = (tid & 7) * 4;
      float4 f = *(const float4*)(Kbase + (size_t)(k0 + row) * DK + c4);
      uint2 h, l;
      h.x = pack_hi2(f.x, f.y); h.y = pack_hi2(f.z, f.w);
      l.x = pack_hi2(f.x - trunc_bf(f.x), f.y - trunc_bf(f.y));
      l.y = pack_hi2(f.z - trunc_bf(f.z), f.w - trunc_bf(f.w));
      *(uint2*)&Khi_[row * LDSW + c4] = h;
      *(uint2*)&Klo_[row * LDSW + c4] = l;
    }
    {
      int kk = (tid & 15) * 2, c4 = (tid >> 4) * 4;
      const float* vp = Vbase + (size_t)(k0 + kk) * DV + c4;
      float4 a = *(const float4*)vp;
      float4 b = *(const float4*)(vp + DV);
      float af[4] = {a.x, a.y, a.z, a.w};
      float bf_[4] = {b.x, b.y, b.z, b.w};
#pragma unroll
      for (int jj = 0; jj < 4; ++jj) {
        *(unsigned*)&Vthi_[(c4 + jj) * LDSW + kk] = pack_hi2(af[jj], bf_[jj]);
        *(unsigned*)&Vtlo_[(c4 + jj) * LDSW + kk] =
            pack_hi2(af[jj] - trunc_bf(af[jj]), bf_[jj] - trunc_bf(bf_[jj]));
      }
    }
    __syncthreads();

    if (k0 > q_wave_max) continue;

#pragma unroll
    for (int k16 = 0; k16 < 2; ++k16) {
      const int kcol0 = k16 * 16;
      bf16x8 khi = *(const bf16x8*)&Khi_[(kcol0 + m) * LDSW + g * 8];
      bf16x8 klo = *(const bf16x8*)&Klo_[(kcol0 + m) * LDSW + g * 8];
      f32x4 sc = {0.f, 0.f, 0.f, 0.f};
      sc = __builtin_amdgcn_mfma_f32_16x16x32_bf16(qhi, khi, sc, 0, 0, 0);
      sc = __builtin_amdgcn_mfma_f32_16x16x32_bf16(qhi, klo, sc, 0, 0, 0);
      sc = __builtin_amdgcn_mfma_f32_16x16x32_bf16(qlo, khi, sc, 0, 0, 0);
      const int k_abs = k0 + kcol0 + m;
      const int kcol  = kcol0 + m;
#pragma unroll
      for (int r = 0; r < 4; ++r) {
        float x  = sc[r] * SCALE;
        float a3 = __builtin_fmaf(x, 0.3333333333333333f, 1.0f);
        float a2 = __builtin_fmaf(x * 0.5f, a3, 1.0f);
        float wvv = __builtin_fmaf(x, a2, 1.0f);
        wvv = (k_abs <= q_lane0 + r) ? wvv : 0.0f;
        zacc[r] += wvv;
        float wl = wvv - trunc_bf(wvv);
        unsigned packed = (__float_as_uint(wvv) >> 16) |
                          (__float_as_uint(wl) & 0xffff0000u);
        const int q = g * 4 + r;
        Wp[wid][q * 32 + (((kcol >> 2) ^ (q & 7)) << 2) + (kcol & 3)] = packed;
      }
    }

    uint4 pa = *(const uint4*)&Wp[wid][m * 32 + (((2 * g) ^ (m & 7)) << 2)];
    uint4 pb = *(const uint4*)&Wp[wid][m * 32 + (((2 * g + 1) ^ (m & 7)) << 2)];
    union { bf16x8 v; unsigned u[4]; } WH, WL;
    WH.u[0] = (pa.x & 0xffffu) | (pa.y << 16);
    WH.u[1] = (pa.z & 0xffffu) | (pa.w << 16);
    WH.u[2] = (pb.x & 0xffffu) | (pb.y << 16);
    WH.u[3] = (pb.z & 0xffffu) | (pb.w << 16);
    WL.u[0] = (pa.x >> 16) | (pa.y & 0xffff0000u);
    WL.u[1] = (pa.z >> 16) | (pa.w & 0xffff0000u);
    WL.u[2] = (pb.x >> 16) | (pb.y & 0xffff0000u);
    WL.u[3] = (pb.z >> 16) | (pb.w & 0xffff0000u);

#pragma unroll
    for (int ct = 0; ct < 4; ++ct) {
      bf16x8 vhi = *(const bf16x8*)&Vthi_[(ct * 16 + m) * LDSW + g * 8];
      bf16x8 vlo = *(const bf16x8*)&Vtlo_[(ct * 16 + m) * LDSW + g * 8];
      acc[ct] = __builtin_amdgcn_mfma_f32_16x16x32_bf16(WH.v, vhi, acc[ct], 0, 0, 0);
      acc[ct] = __builtin_amdgcn_mfma_f32_16x16x32_bf16(WH.v, vlo, acc[ct], 0, 0, 0);
      acc[ct] = __builtin_amdgcn_mfma_f32_16x16x32_bf16(WL.v, vhi, acc[ct], 0, 0, 0);
    }
  }

  float invz[4];
#pragma unroll
  for (int r = 0; r < 4; ++r) {
    float z = zacc[r];
    z += __shfl_xor(z, 1); z += __shfl_xor(z, 2);
    z += __shfl_xor(z, 4); z += __shfl_xor(z, 8);
    invz[r] = 1.0f / z;
  }

  float* ob = Outg + ((size_t)bh * T_SEQ + (q0 + wq)) * DV;
#pragma unroll
  for (int ct = 0; ct < 4; ++ct)
#pragma unroll
    for (int r = 0; r < 4; ++r)
      ob[(g * 4 + r) * DV + ct * 16 + m] = acc[ct][r] * invz[r];
}

}  // namespace

extern "C" void kernel_launch(void* const* d_in, const int* in_sizes, int n_in,
                              void* d_out, int out_size, void* d_ws, size_t ws_size,
                              hipStream_t stream) {
  const float* Q = (const float*)d_in[0];
  const float* K = (const float*)d_in[1];
  const float* V = (const float*)d_in[2];
  float* Out = (float*)d_out;

  if (ws_size >= WS_NEED && d_ws != nullptr) {
    u16* khf  = (u16*)((char*)d_ws + KHF_OFF);
    u16* vthi = (u16*)((char*)d_ws + VTHI_OFF);

    hipLaunchKernelGGL(pack_kv, dim3(4096), dim3(256), 0, stream, K, V, khf, vthi);
    hipLaunchKernelGGL(taylor_attn_v7, dim3(1024), dim3(256), 0, stream,
                       Q, khf, vthi, Out);
  } else {
    hipLaunchKernelGGL(taylor_attn_fb, dim3(1024), dim3(256), 0, stream,
                       Q, K, V, Out);
  }
}